// Round 10
// baseline (210.520 us; speedup 1.0000x reference)
//
#include <hip/hip_runtime.h>
#include <hip/hip_bf16.h>
#include <stdint.h>

typedef float   f32x4  __attribute__((ext_vector_type(4)));
typedef __bf16  bf16x8 __attribute__((ext_vector_type(8)));
typedef unsigned short u16x4 __attribute__((ext_vector_type(4)));
typedef unsigned short u16x8 __attribute__((ext_vector_type(8)));

__device__ __forceinline__ uint16_t f2b(float x) {
  union { float f; uint32_t u; } c; c.f = x;
  uint32_t u = c.u;
  return (uint16_t)((u + 0x7FFFu + ((u >> 16) & 1u)) >> 16);
}
__device__ __forceinline__ float b2f(uint16_t x) {
  union { uint32_t u; float f; } c; c.u = ((uint32_t)x) << 16;
  return c.f;
}

__device__ __forceinline__ f32x4 mfma32(bf16x8 a, bf16x8 b, f32x4 c) {
  return __builtin_amdgcn_mfma_f32_16x16x32_bf16(a, b, c, 0, 0, 0);
}

#define GLDS16(g, l) __builtin_amdgcn_global_load_lds( \
    (const __attribute__((address_space(1))) void*)(const void*)(g), \
    (__attribute__((address_space(3))) void*)(void*)(l), 16, 0, 0)

#define WAITVM(N) asm volatile("s_waitcnt vmcnt(" #N ")" ::: "memory")
#define WAITLGKM0 asm volatile("s_waitcnt lgkmcnt(0)" ::: "memory")
#define BAR() __builtin_amdgcn_s_barrier()

// -------- weight transposes + bias concat (z=10) + fp32->bf16 (z=11..16) ----
__global__ __launch_bounds__(256) void wtrans_all(
    const float* __restrict__ W0, const float* __restrict__ W1,
    const float* __restrict__ W2, const float* __restrict__ W3,
    const float* __restrict__ W4, const float* __restrict__ W5,
    const float* __restrict__ W6, const float* __restrict__ W7,
    const float* __restrict__ W8, const float* __restrict__ W9,
    uint16_t* __restrict__ WT,
    const float* __restrict__ bq, const float* __restrict__ bk,
    const float* __restrict__ bv, const float* __restrict__ sbq,
    const float* __restrict__ sbk, float* __restrict__ biasc,
    const float* __restrict__ id_x, const float* __restrict__ side,
    uint16_t* __restrict__ xb, uint16_t* __restrict__ sdb) {
  __shared__ float tl[32][33];
  const int tx = threadIdx.x, ty = threadIdx.y; // (32, 8)
  if (blockIdx.z >= 11) {
    // fp32 -> bf16 slices: zi 0..1 -> id_x (2M), zi 2..5 -> side (4M)
    size_t zi = blockIdx.z - 11;
    size_t base = ((zi * 1024 + blockIdx.y * 32 + blockIdx.x) * 256
                   + ty * 32 + tx) * 4;
    const float* in; uint16_t* out;
    if (base < 2097152) { in = id_x; out = xb; }
    else { in = side; out = sdb; base -= 2097152; }
    f32x4 v = *(const f32x4*)(in + base);
    u16x4 o;
    o[0] = f2b(v[0]); o[1] = f2b(v[1]); o[2] = f2b(v[2]); o[3] = f2b(v[3]);
    *(u16x4*)(out + base) = o;
    return;
  }
  if (blockIdx.z == 10) {
    int i = (blockIdx.y * 32 + blockIdx.x) * 256 + ty * 32 + tx;
    if (i < 7168) {
      int seg = i >> 10, off = i & 1023;
      float v;
      switch (seg) {
        case 0: v = bq[off]; break;
        case 1: v = bk[off]; break;
        case 2: v = bv[off]; break;
        case 3: v = sbq[off]; break;
        case 4: v = sbk[off]; break;
        case 5: v = sbq[1024 + off]; break;
        default: v = sbk[1024 + off]; break;
      }
      biasc[i] = v;
    }
    return;
  }
  const float* W;
  switch (blockIdx.z) {
    case 0: W = W0; break; case 1: W = W1; break; case 2: W = W2; break;
    case 3: W = W3; break; case 4: W = W4; break; case 5: W = W5; break;
    case 6: W = W6; break; case 7: W = W7; break; case 8: W = W8; break;
    default: W = W9; break;
  }
  uint16_t* dst = WT + (size_t)blockIdx.z * 1048576;
  const int n0 = blockIdx.x * 32, k0 = blockIdx.y * 32;
#pragma unroll
  for (int i = 0; i < 32; i += 8)
    tl[ty + i][tx] = W[(size_t)(k0 + ty + i) * 1024 + n0 + tx];
  __syncthreads();
#pragma unroll
  for (int i = 0; i < 32; i += 8)
    dst[(size_t)(n0 + ty + i) * 1024 + k0 + tx] = f2b(tl[tx][ty + i]);
}

// ---------------- merged projection GEMM (qkv + side0 + side1), 896 blocks ----
// XOR-swizzled row-major LDS (0 conflicts) + 3-buffer 2-deep prefetch with
// BK=64 super-iters: 8 global_load_lds per stage, 32 MFMA per barrier-pair.
__global__ __launch_bounds__(256) void proj_k(
    const uint16_t* __restrict__ xb, const uint16_t* __restrict__ sdb,
    const uint16_t* __restrict__ WT, const float* __restrict__ biasc,
    uint16_t* __restrict__ qkv, uint16_t* __restrict__ sqk0,
    uint16_t* __restrict__ sqk1, uint16_t* __restrict__ vT) {
  __shared__ uint16_t As[3][8192];
  __shared__ uint16_t Bs[3][8192];
  const int bid = blockIdx.x;
  const uint16_t* A; const uint16_t* BT; const float* bias; uint16_t* C;
  int lda, ldc, bx, by;
  bool dovt = false;
  if (bid < 384) {
    bx = bid % 24; by = bid / 24;
    A = xb; lda = 1024; BT = WT; bias = biasc; C = qkv; ldc = 3072;
    dovt = bx >= 16;
  } else if (bid < 640) {
    int r = bid - 384; bx = r & 15; by = r >> 4;
    A = sdb; lda = 2048; BT = WT + 3145728; bias = biasc + 3072;
    C = sqk0; ldc = 2048;
  } else {
    int r = bid - 640; bx = r & 15; by = r >> 4;
    A = sdb + 1024; lda = 2048; BT = WT + 5242880; bias = biasc + 5120;
    C = sqk1; ldc = 2048;
  }
  const int t = threadIdx.x;
  const int lane = t & 63, w = t >> 6;
  const int wr = w >> 1, wc = w & 1;
  const int l15 = lane & 15, g = lane >> 4;
  const int bm0 = by * 128, bn0 = bx * 128;

  const int scol = ((t & 3) ^ ((t >> 3) & 3)) * 8;
  const uint16_t* ga = A  + (size_t)(bm0 + (t >> 2)) * lda  + scol;
  const uint16_t* gb = BT + (size_t)(bn0 + (t >> 2)) * 1024 + scol;
  const int gsw = (g ^ ((l15 >> 1) & 3)) * 8;

#define GSTAGE(bufi, k0) do { \
    GLDS16(ga + (k0),                          &As[bufi][t * 8]); \
    GLDS16(ga + (size_t)64 * lda + (k0),       &As[bufi][2048 + t * 8]); \
    GLDS16(ga + (k0) + 32,                     &As[bufi][4096 + t * 8]); \
    GLDS16(ga + (size_t)64 * lda + (k0) + 32,  &As[bufi][6144 + t * 8]); \
    GLDS16(gb + (k0),                          &Bs[bufi][t * 8]); \
    GLDS16(gb + 64 * 1024 + (k0),              &Bs[bufi][2048 + t * 8]); \
    GLDS16(gb + (k0) + 32,                     &Bs[bufi][4096 + t * 8]); \
    GLDS16(gb + 64 * 1024 + (k0) + 32,         &Bs[bufi][6144 + t * 8]); } while (0)

  f32x4 acc[4][4] = {};
  GSTAGE(0, 0);
  GSTAGE(1, 64);
  int cur = 0;
  for (int it = 0; it < 16; it++) {
    if (it < 14) {
      int pre = cur + 2; if (pre >= 3) pre -= 3;
      GSTAGE(pre, (it + 2) * 64);
      WAITVM(16);
    } else if (it == 14) {
      WAITVM(8);
    } else {
      WAITVM(0);
    }
    BAR();
#pragma unroll
    for (int hf = 0; hf < 2; hf++) {
      const int ho = hf * 4096;
      bf16x8 af[4], bf[4];
#pragma unroll
      for (int i = 0; i < 4; i++)
        af[i] = *(const bf16x8*)&As[cur][ho + (wr * 64 + i * 16 + l15) * 32 + gsw];
#pragma unroll
      for (int i = 0; i < 4; i++)
        bf[i] = *(const bf16x8*)&Bs[cur][ho + (wc * 64 + i * 16 + l15) * 32 + gsw];
#pragma unroll
      for (int mi = 0; mi < 4; mi++)
#pragma unroll
        for (int ni = 0; ni < 4; ni++)
          acc[mi][ni] = mfma32(af[mi], bf[ni], acc[mi][ni]);
    }
    WAITLGKM0;
    BAR();
    cur = (cur + 1 == 3) ? 0 : cur + 1;
  }
#undef GSTAGE

#pragma unroll
  for (int mi = 0; mi < 4; mi++) {
#pragma unroll
    for (int ni = 0; ni < 4; ni++) {
      const int row0 = bm0 + wr * 64 + mi * 16 + g * 4;
      const int col  = bn0 + wc * 64 + ni * 16 + l15;
      const float bc = bias[col];
      u16x4 ov;
#pragma unroll
      for (int r = 0; r < 4; r++) {
        float v = acc[mi][ni][r] + bc;
        ov[r] = f2b(v);
        C[(size_t)(row0 + r) * ldc + col] = ov[r];
      }
      if (dovt) {
        const int cc = col - 2048, hh = cc >> 6, dd = cc & 63;
        const int bb = row0 >> 10, s0 = row0 & 1023;
        *(u16x4*)&vT[((size_t)((bb * 16 + hh) * 64 + dd)) * 1024 + s0] = ov;
      }
    }
  }
}

// ---------------- GEMM 64x64 (512 blocks; BK=64 super-iters; 2-deep) ----
enum { EPI_BF16 = 0, EPI_RES = 1, EPI_GELU = 2 };

template<int EPI>
__global__ __launch_bounds__(256) void gemm64_k(
    const uint16_t* __restrict__ A, int lda,
    const uint16_t* __restrict__ BT,
    const float* __restrict__ bias,
    const float* __restrict__ res,
    void* __restrict__ Cv, int ldc) {
  __shared__ uint16_t As[3][4096];
  __shared__ uint16_t Bs[3][4096];
  const int t = threadIdx.x;
  const int lane = t & 63, w = t >> 6;
  const int wr = w >> 1, wc = w & 1;
  const int l15 = lane & 15, g = lane >> 4;
  const int bm0 = blockIdx.y * 64, bn0 = blockIdx.x * 64;

  const int scol = ((t & 3) ^ ((t >> 3) & 3)) * 8;
  const uint16_t* ga = A  + (size_t)(bm0 + (t >> 2)) * lda  + scol;
  const uint16_t* gb = BT + (size_t)(bn0 + (t >> 2)) * 1024 + scol;
  const int gsw = (g ^ ((l15 >> 1) & 3)) * 8;

#define GSTAGE64(bufi, k0) do { \
    GLDS16(ga + (k0),      &As[bufi][t * 8]); \
    GLDS16(ga + (k0) + 32, &As[bufi][2048 + t * 8]); \
    GLDS16(gb + (k0),      &Bs[bufi][t * 8]); \
    GLDS16(gb + (k0) + 32, &Bs[bufi][2048 + t * 8]); } while (0)

  f32x4 acc[2][2] = {};
  GSTAGE64(0, 0);
  GSTAGE64(1, 64);
  int cur = 0;
  for (int it = 0; it < 16; it++) {
    if (it < 14) {
      int pre = cur + 2; if (pre >= 3) pre -= 3;
      GSTAGE64(pre, (it + 2) * 64);
      WAITVM(8);
    } else if (it == 14) {
      WAITVM(4);
    } else {
      WAITVM(0);
    }
    BAR();
#pragma unroll
    for (int hf = 0; hf < 2; hf++) {
      const int ho = hf * 2048;
      bf16x8 af[2], bf[2];
#pragma unroll
      for (int i = 0; i < 2; i++)
        af[i] = *(const bf16x8*)&As[cur][ho + (wr * 32 + i * 16 + l15) * 32 + gsw];
#pragma unroll
      for (int i = 0; i < 2; i++)
        bf[i] = *(const bf16x8*)&Bs[cur][ho + (wc * 32 + i * 16 + l15) * 32 + gsw];
#pragma unroll
      for (int mi = 0; mi < 2; mi++)
#pragma unroll
        for (int ni = 0; ni < 2; ni++)
          acc[mi][ni] = mfma32(af[mi], bf[ni], acc[mi][ni]);
    }
    WAITLGKM0;
    BAR();
    cur = (cur + 1 == 3) ? 0 : cur + 1;
  }
#undef GSTAGE64

#pragma unroll
  for (int mi = 0; mi < 2; mi++) {
#pragma unroll
    for (int ni = 0; ni < 2; ni++) {
      const int row0 = bm0 + wr * 32 + mi * 16 + g * 4;
      const int col  = bn0 + wc * 32 + ni * 16 + l15;
      const float bc = bias[col];
#pragma unroll
      for (int r = 0; r < 4; r++) {
        float v = acc[mi][ni][r] + bc;
        const size_t idx = (size_t)(row0 + r) * ldc + col;
        if constexpr (EPI == EPI_RES) {
          ((float*)Cv)[idx] = v + res[idx];
        } else if constexpr (EPI == EPI_GELU) {
          float gl = 0.5f * v * (1.0f + erff(v * 0.70710678118654752f));
          ((uint16_t*)Cv)[idx] = f2b(gl);
        } else {
          ((uint16_t*)Cv)[idx] = f2b(v);
        }
      }
    }
  }
}

// ---------------- attention pass 1: Z partials (k-split, 3-buffer 2-deep) ----
__global__ __launch_bounds__(256) void attn_z(
    const uint16_t* __restrict__ qkv,
    const uint16_t* __restrict__ sqk0,
    const uint16_t* __restrict__ sqk1,
    float* __restrict__ zp) {
  __shared__ uint16_t Ks0[3][2048];
  __shared__ uint16_t Ks1[3][2048];
  __shared__ uint16_t Ks2[3][2048];
  const int t = threadIdx.x;
  const int lane = t & 63, w = t >> 6;
  const int l15 = lane & 15, g = lane >> 4;
  const int bid = blockIdx.x;
  const int xcd = bid & 7, idx = bid >> 3;
  const int grp = xcd * 8 + (idx >> 4);
  const int qt = idx & 15;
  const int hb = grp >> 1, kc = grp & 1;
  const int b = hb >> 4, h = hb & 15;
  const int q0 = qt * 64 + w * 16;
  const float scl2 = 0.03125f * 1.44269504088896f;
  const size_t rq = (size_t)(b * 1024 + q0 + l15);

  bf16x8 qf[3][2];
  {
    const uint16_t* p = qkv + rq * 3072 + h * 64 + g * 8;
    qf[0][0] = *(const bf16x8*)p; qf[0][1] = *(const bf16x8*)(p + 32);
    p = sqk0 + rq * 2048 + h * 64 + g * 8;
    qf[1][0] = *(const bf16x8*)p; qf[1][1] = *(const bf16x8*)(p + 32);
    p = sqk1 + rq * 2048 + h * 64 + g * 8;
    qf[2][0] = *(const bf16x8*)p; qf[2][1] = *(const bf16x8*)(p + 32);
  }

  const int p_   = t & 15;
  const int gg_  = (t >> 4) & 3;
  const int hf_  = (t >> 6) & 1;
  const int stq_ = t >> 7;
  const int srow   = (p_ >> 2) * 8 + stq_ * 4 + (p_ & 3) + kc * 512;
  const int kcolel = hf_ * 32 + gg_ * 8;

  const uint16_t* pk0 = qkv  + (size_t)b * 1024 * 3072 + 1024 + h * 64
                      + (size_t)srow * 3072 + kcolel;
  const uint16_t* pk1 = sqk0 + (size_t)b * 1024 * 2048 + 1024 + h * 64
                      + (size_t)srow * 2048 + kcolel;
  const uint16_t* pk2 = sqk1 + (size_t)b * 1024 * 2048 + 1024 + h * 64
                      + (size_t)srow * 2048 + kcolel;

#define STAGE3(bufi) do { \
    GLDS16(pk0, &Ks0[bufi][t * 8]); \
    GLDS16(pk1, &Ks1[bufi][t * 8]); \
    GLDS16(pk2, &Ks2[bufi][t * 8]); \
    pk0 += 32 * 3072; pk1 += 32 * 2048; pk2 += 32 * 2048; } while (0)

  float z0 = 0.f, z1 = 0.f, z2 = 0.f;
  STAGE3(0);
  STAGE3(1);
  int cur = 0;
  for (int kt = 0; kt < 16; kt++) {
    if (kt < 14) {
      int pre = cur + 2; if (pre >= 3) pre -= 3;
      STAGE3(pre);
      WAITVM(6);
    } else if (kt == 14) {
      WAITVM(3);
    } else {
      WAITVM(0);
    }
    BAR();
#pragma unroll
    for (int st = 0; st < 2; st++) {
      f32x4 c0 = {}, c1 = {}, c2 = {};
      c0 = mfma32(*(const bf16x8*)&Ks0[cur][st * 1024 + lane * 8],       qf[0][0], c0);
      c0 = mfma32(*(const bf16x8*)&Ks0[cur][st * 1024 + 512 + lane * 8], qf[0][1], c0);
      c1 = mfma32(*(const bf16x8*)&Ks1[cur][st * 1024 + lane * 8],       qf[1][0], c1);
      c1 = mfma32(*(const bf16x8*)&Ks1[cur][st * 1024 + 512 + lane * 8], qf[1][1], c1);
      c2 = mfma32(*(const bf16x8*)&Ks2[cur][st * 1024 + lane * 8],       qf[2][0], c2);
      c2 = mfma32(*(const bf16x8*)&Ks2[cur][st * 1024 + 512 + lane * 8], qf[2][1], c2);
#pragma unroll
      for (int r = 0; r < 4; r++) {
        z0 += __builtin_amdgcn_exp2f(c0[r] * scl2);
        z1 += __builtin_amdgcn_exp2f(c1[r] * scl2);
        z2 += __builtin_amdgcn_exp2f(c2[r] * scl2);
      }
    }
    WAITLGKM0;
    BAR();
    cur = (cur + 1 == 3) ? 0 : cur + 1;
  }
#undef STAGE3
  z0 += __shfl_xor(z0, 16, 64); z0 += __shfl_xor(z0, 32, 64);
  z1 += __shfl_xor(z1, 16, 64); z1 += __shfl_xor(z1, 32, 64);
  z2 += __shfl_xor(z2, 16, 64); z2 += __shfl_xor(z2, 32, 64);
  if (lane < 16) {
    const int qi = hb * 1024 + q0 + l15;
    zp[kc * 32768 + qi]          = z0;
    zp[65536 + kc * 32768 + qi]  = z1;
    zp[131072 + kc * 32768 + qi] = z2;
  }
}

// ---------------- attention pass 2 (zred inlined): partial O ----------------
__global__ __launch_bounds__(256) void attn_o(
    const uint16_t* __restrict__ qkv,
    const uint16_t* __restrict__ sqk0,
    const uint16_t* __restrict__ sqk1,
    const uint16_t* __restrict__ vT,
    const float* __restrict__ zp,
    uint16_t* __restrict__ op) {
  __shared__ uint16_t Ks0[2][2048];
  __shared__ uint16_t Ks1[2][2048];
  __shared__ uint16_t Ks2[2][2048];
  __shared__ uint16_t Vs[2][2048];
  const int t = threadIdx.x;
  const int lane = t & 63, w = t >> 6;
  const int l15 = lane & 15, g = lane >> 4;
  const int bid = blockIdx.x;
  const int xcd = bid & 7, idx = bid >> 3;
  const int grp = xcd * 8 + (idx >> 4);
  const int qt = idx & 15;
  const int hb = grp >> 1, kc = grp & 1;
  const int b = hb >> 4, h = hb & 15;
  const int q0 = qt * 64 + w * 16;
  const float scl2 = 0.03125f * 1.44269504088896f;
  const size_t rq = (size_t)(b * 1024 + q0 + l15);

  bf16x8 qf[3][2];
  {
    const uint16_t* p = qkv + rq * 3072 + h * 64 + g * 8;
    qf[0][0] = *(const bf16x8*)p; qf[0][1] = *(const bf16x8*)(p + 32);
    p = sqk0 + rq * 2048 + h * 64 + g * 8;
    qf[1][0] = *(const bf16x8*)p; qf[1][1] = *(const bf16x8*)(p + 32);
    p = sqk1 + rq * 2048 + h * 64 + g * 8;
    qf[2][0] = *(const bf16x8*)p; qf[2][1] = *(const bf16x8*)(p + 32);
  }
  const int qi = hb * 1024 + q0 + l15;
  const float lz0 = __builtin_amdgcn_logf(zp[qi] + zp[qi + 32768]);
  const float lz1 = __builtin_amdgcn_logf(zp[qi + 65536] + zp[qi + 98304]);
  const float lz2 = __builtin_amdgcn_logf(zp[qi + 131072] + zp[qi + 163840]);

  const int p_   = t & 15;
  const int gg_  = (t >> 4) & 3;
  const int hf_  = (t >> 6) & 1;
  const int stq_ = t >> 7;
  const int srow   = (p_ >> 2) * 8 + stq_ * 4 + (p_ & 3) + kc * 512;
  const int kcolel = hf_ * 32 + gg_ * 8;

  const uint16_t* pk0 = qkv  + (size_t)b * 1024 * 3072 + 1024 + h * 64
                      + (size_t)srow * 3072 + kcolel;
  const uint16_t* pk1 = sqk0 + (size_t)b * 1024 * 2048 + 1024 + h * 64
                      + (size_t)srow * 2048 + kcolel;
  const uint16_t* pk2 = sqk1 + (size_t)b * 1024 * 2048 + 1024 + h * 64
                      + (size_t)srow * 2048 + kcolel;
  const uint16_t* pv  = vT + ((size_t)hb * 64 + (t >> 6) * 16 + p_) * 1024
                      + kc * 512 + gg_ * 8;

#define STAGE4(bufi) do { \
    GLDS16(pk0, &Ks0[bufi][t * 8]); \
    GLDS16(pk1, &Ks1[bufi][t * 8]); \
    GLDS16(pk2, &Ks2[bufi][t * 8]); \
    GLDS16(pv,  &Vs[bufi][t * 8]); \
    pk0 += 32 * 3072; pk1 += 32 * 2048; pk2 += 32 * 2048; pv += 32; } while (0)

  f32x4 accO[4] = {};
  int cur = 0;
  STAGE4(0);
  for (int kt = 0; kt < 16; kt++) {
    if (kt < 15) { STAGE4(cur ^ 1); WAITVM(4); }
    else WAITVM(0);
    BAR();
    u16x8 pu;
#pragma unroll
    for (int sub = 0; sub < 2; sub++) {
      f32x4 c0 = {}, c1 = {}, c2 = {};
      c0 = mfma32(*(const bf16x8*)&Ks0[cur][sub * 1024 + lane * 8],       qf[0][0], c0);
      c0 = mfma32(*(const bf16x8*)&Ks0[cur][sub * 1024 + 512 + lane * 8], qf[0][1], c0);
      c1 = mfma32(*(const bf16x8*)&Ks1[cur][sub * 1024 + lane * 8],       qf[1][0], c1);
      c1 = mfma32(*(const bf16x8*)&Ks1[cur][sub * 1024 + 512 + lane * 8], qf[1][1], c1);
      c2 = mfma32(*(const bf16x8*)&Ks2[cur][sub * 1024 + lane * 8],       qf[2][0], c2);
      c2 = mfma32(*(const bf16x8*)&Ks2[cur][sub * 1024 + 512 + lane * 8], qf[2][1], c2);
#pragma unroll
      for (int r = 0; r < 4; r++) {
        float m = fmaxf(fmaxf(c0[r] * scl2 - lz0, c1[r] * scl2 - lz1),
                        c2[r] * scl2 - lz2);
        pu[sub * 4 + r] = f2b(__builtin_amdgcn_exp2f(m));
      }
    }
    const bf16x8 pf = __builtin_bit_cast(bf16x8, pu);
#pragma unroll
    for (int dt = 0; dt < 4; dt++) {
      bf16x8 vf = *(const bf16x8*)&Vs[cur][dt * 512 + lane * 8];
      accO[dt] = mfma32(vf, pf, accO[dt]);
    }
    WAITLGKM0;
    BAR();
    cur ^= 1;
  }
#undef STAGE4

  uint16_t* ob = op + (size_t)kc * 2097152 + rq * 1024 + h * 64;
#pragma unroll
  for (int dt = 0; dt < 4; dt++) {
    u16x4 o4;
#pragma unroll
    for (int r = 0; r < 4; r++) o4[r] = f2b(accO[dt][r]);
    *(u16x4*)(ob + dt * 16 + g * 4) = o4;
  }
}

// ---------------- O partial reduce: Ob = bf16(op0 + op1) ----------------
__global__ __launch_bounds__(256) void ored_k(const uint16_t* __restrict__ op0,
                                              const uint16_t* __restrict__ op1,
                                              uint16_t* __restrict__ Ob) {
  int i = (blockIdx.x * 256 + threadIdx.x) * 4;
  u16x4 a = *(const u16x4*)(op0 + i);
  u16x4 b = *(const u16x4*)(op1 + i);
  u16x4 o;
#pragma unroll
  for (int j = 0; j < 4; j++) o[j] = f2b(b2f(a[j]) + b2f(b[j]));
  *(u16x4*)(Ob + i) = o;
}

// ---------------- LayerNorm over rows of 1024 fp32, optional bf16 copy ----------------
template<int WB>
__global__ __launch_bounds__(256) void ln_k(const float* __restrict__ X,
                                            const float* __restrict__ G,
                                            const float* __restrict__ Bt,
                                            float* __restrict__ Yf,
                                            uint16_t* __restrict__ Yb) {
  const int row = blockIdx.x, t = threadIdx.x;
  const int lane = t & 63, w = t >> 6;
  const size_t base = (size_t)row * 1024 + t * 4;
  f32x4 x = *(const f32x4*)(X + base);
  float s  = x[0] + x[1] + x[2] + x[3];
  float s2 = x[0] * x[0] + x[1] * x[1] + x[2] * x[2] + x[3] * x[3];
#pragma unroll
  for (int o = 1; o < 64; o <<= 1) {
    s  += __shfl_xor(s,  o, 64);
    s2 += __shfl_xor(s2, o, 64);
  }
  __shared__ float red[8];
  if (lane == 0) { red[w] = s; red[4 + w] = s2; }
  __syncthreads();
  s  = red[0] + red[1] + red[2] + red[3];
  s2 = red[4] + red[5] + red[6] + red[7];
  const float mean = s * (1.0f / 1024.0f);
  const float rstd = rsqrtf(s2 * (1.0f / 1024.0f) - mean * mean + 1e-5f);
  f32x4 gv = *(const f32x4*)(G + t * 4);
  f32x4 bv = *(const f32x4*)(Bt + t * 4);
  f32x4 y;
#pragma unroll
  for (int i = 0; i < 4; i++) y[i] = (x[i] - mean) * rstd * gv[i] + bv[i];
  *(f32x4*)(Yf + base) = y;
  if constexpr (WB) {
    u16x4 o;
#pragma unroll
    for (int i = 0; i < 4; i++) o[i] = f2b(y[i]);
    *(u16x4*)(Yb + base) = o;
  }
}

// ---------------- host ----------------
extern "C" void kernel_launch(void* const* d_in, const int* in_sizes, int n_in,
                              void* d_out, int out_size, void* d_ws, size_t ws_size,
                              hipStream_t stream) {
  (void)in_sizes; (void)n_in; (void)out_size;
  const float* id_x = (const float*)d_in[0];
  const float* side = (const float*)d_in[1];
  const float* Wq  = (const float*)d_in[3];
  const float* bq  = (const float*)d_in[4];
  const float* Wk  = (const float*)d_in[5];
  const float* bk  = (const float*)d_in[6];
  const float* Wv  = (const float*)d_in[7];
  const float* bv  = (const float*)d_in[8];
  const float* sWq = (const float*)d_in[9];
  const float* sbq = (const float*)d_in[10];
  const float* sWk = (const float*)d_in[11];
  const float* sbk = (const float*)d_in[12];
  const float* Wo  = (const float*)d_in[13];
  const float* bo  = (const float*)d_in[14];
  const float* W1  = (const float*)d_in[15];
  const float* b1  = (const float*)d_in[16];
  const float* W2  = (const float*)d_in[17];
  const float* b2  = (const float*)d_in[18];
  const float* g1  = (const float*)d_in[19];
  const float* be1 = (const float*)d_in[20];
  const float* g2  = (const float*)d_in[21];
  const float* be2 = (const float*)d_in[22];

  char* ws = (char*)d_ws;
  const size_t oWT   = 0;                       // 10x 1024x1024 bf16 = 20,971,520
  const size_t oBias = 20971520;                // 7168 f32 = 28,672
  const size_t oZP   = 21000192;                // 3*65536 f32 = 786,432
  const size_t oC    = 22179840;                // 4 MB: xb -> op0
  const size_t oD    = 26374144;                // 8 MB: sdb -> op1 | Ob
  const size_t oE    = 34762752;                // 32 MB
  const size_t total = oE + 33554432;           // 68,317,184
  if (ws_size < total) return;

  uint16_t* WT    = (uint16_t*)(ws + oWT);
  float*    biasc = (float*)(ws + oBias);
  float*    zp    = (float*)(ws + oZP);
  uint16_t* xb    = (uint16_t*)(ws + oC);
  uint16_t* op0   = (uint16_t*)(ws + oC);          // aliases xb (dead post-proj)
  uint16_t* sdb   = (uint16_t*)(ws + oD);
  uint16_t* Ob    = (uint16_t*)(ws + oD + 4194304);
  char* E = ws + oE;
  uint16_t* qkv  = (uint16_t*)(E);                  // 12 MB
  uint16_t* sqk0 = (uint16_t*)(E + 12582912);       // 8 MB
  uint16_t* sqk1 = (uint16_t*)(E + 20971520);       // 8 MB
  uint16_t* vTp  = (uint16_t*)(E + 29360128);       // 4 MB
  // post-attention aliases (qkv/sqk/vT dead after attn_o):
  float*    x1   = (float*)(E);                     // 8 MB
  float*    x1n  = (float*)(E + 8388608);           // 8 MB
  uint16_t* x1nb = (uint16_t*)(E + 16777216);       // 4 MB
  uint16_t* hb   = (uint16_t*)(E + 20971520);       // 4 MB
  float*    x2   = (float*)(E + 25165824);          // 8 MB

  wtrans_all<<<dim3(32, 32, 17), dim3(32, 8), 0, stream>>>(
      Wq, Wk, Wv, sWq, sWk, sWq + 1048576, sWk + 1048576, Wo, W1, W2, WT,
      bq, bk, bv, sbq, sbk, biasc, id_x, side, xb, sdb);

  proj_k<<<896, 256, 0, stream>>>(xb, sdb, WT, biasc, qkv, sqk0, sqk1, vTp);

  attn_z<<<1024, 256, 0, stream>>>(qkv, sqk0, sqk1, zp);
  attn_o<<<1024, 256, 0, stream>>>(qkv, sqk0, sqk1, vTp, zp, op0);
  ored_k<<<2048, 256, 0, stream>>>(op0, op0 + 2097152, Ob);

  gemm64_k<EPI_RES><<<dim3(16, 32), 256, 0, stream>>>(Ob, 1024, WT + 7340032, bo, id_x, x1, 1024);
  ln_k<1><<<2048, 256, 0, stream>>>(x1, g1, be1, x1n, x1nb);
  gemm64_k<EPI_GELU><<<dim3(16, 32), 256, 0, stream>>>(x1nb, 1024, WT + 8388608, b1, nullptr, hb, 1024);
  gemm64_k<EPI_RES><<<dim3(16, 32), 256, 0, stream>>>(hb, 1024, WT + 9437184, b2, x1n, x2, 1024);
  ln_k<0><<<2048, 256, 0, stream>>>(x2, g2, be2, (float*)d_out, nullptr);
}

// Round 11
// 183.679 us; speedup vs baseline: 1.1461x; 1.1461x over previous
//
#include <hip/hip_runtime.h>
#include <hip/hip_bf16.h>
#include <stdint.h>

typedef float   f32x4  __attribute__((ext_vector_type(4)));
typedef __bf16  bf16x8 __attribute__((ext_vector_type(8)));
typedef unsigned short u16x4 __attribute__((ext_vector_type(4)));
typedef unsigned short u16x8 __attribute__((ext_vector_type(8)));

__device__ __forceinline__ uint16_t f2b(float x) {
  union { float f; uint32_t u; } c; c.f = x;
  uint32_t u = c.u;
  return (uint16_t)((u + 0x7FFFu + ((u >> 16) & 1u)) >> 16);
}
__device__ __forceinline__ float b2f(uint16_t x) {
  union { uint32_t u; float f; } c; c.u = ((uint32_t)x) << 16;
  return c.f;
}

__device__ __forceinline__ f32x4 mfma32(bf16x8 a, bf16x8 b, f32x4 c) {
  return __builtin_amdgcn_mfma_f32_16x16x32_bf16(a, b, c, 0, 0, 0);
}

#define GLDS16(g, l) __builtin_amdgcn_global_load_lds( \
    (const __attribute__((address_space(1))) void*)(const void*)(g), \
    (__attribute__((address_space(3))) void*)(void*)(l), 16, 0, 0)

#define WAITVM(N) asm volatile("s_waitcnt vmcnt(" #N ")" ::: "memory")
#define WAITLGKM0 asm volatile("s_waitcnt lgkmcnt(0)" ::: "memory")
#define BAR() __builtin_amdgcn_s_barrier()

// -------- weight transposes + bias concat (z=10) + fp32->bf16 (z=11..16) ----
__global__ __launch_bounds__(256) void wtrans_all(
    const float* __restrict__ W0, const float* __restrict__ W1,
    const float* __restrict__ W2, const float* __restrict__ W3,
    const float* __restrict__ W4, const float* __restrict__ W5,
    const float* __restrict__ W6, const float* __restrict__ W7,
    const float* __restrict__ W8, const float* __restrict__ W9,
    uint16_t* __restrict__ WT,
    const float* __restrict__ bq, const float* __restrict__ bk,
    const float* __restrict__ bv, const float* __restrict__ sbq,
    const float* __restrict__ sbk, float* __restrict__ biasc,
    const float* __restrict__ id_x, const float* __restrict__ side,
    uint16_t* __restrict__ xb, uint16_t* __restrict__ sdb) {
  __shared__ float tl[32][33];
  const int tx = threadIdx.x, ty = threadIdx.y; // (32, 8)
  if (blockIdx.z >= 11) {
    // fp32 -> bf16 slices: zi 0..1 -> id_x (2M), zi 2..5 -> side (4M)
    size_t zi = blockIdx.z - 11;
    size_t base = ((zi * 1024 + blockIdx.y * 32 + blockIdx.x) * 256
                   + ty * 32 + tx) * 4;
    const float* in; uint16_t* out;
    if (base < 2097152) { in = id_x; out = xb; }
    else { in = side; out = sdb; base -= 2097152; }
    f32x4 v = *(const f32x4*)(in + base);
    u16x4 o;
    o[0] = f2b(v[0]); o[1] = f2b(v[1]); o[2] = f2b(v[2]); o[3] = f2b(v[3]);
    *(u16x4*)(out + base) = o;
    return;
  }
  if (blockIdx.z == 10) {
    int i = (blockIdx.y * 32 + blockIdx.x) * 256 + ty * 32 + tx;
    if (i < 7168) {
      int seg = i >> 10, off = i & 1023;
      float v;
      switch (seg) {
        case 0: v = bq[off]; break;
        case 1: v = bk[off]; break;
        case 2: v = bv[off]; break;
        case 3: v = sbq[off]; break;
        case 4: v = sbk[off]; break;
        case 5: v = sbq[1024 + off]; break;
        default: v = sbk[1024 + off]; break;
      }
      biasc[i] = v;
    }
    return;
  }
  const float* W;
  switch (blockIdx.z) {
    case 0: W = W0; break; case 1: W = W1; break; case 2: W = W2; break;
    case 3: W = W3; break; case 4: W = W4; break; case 5: W = W5; break;
    case 6: W = W6; break; case 7: W = W7; break; case 8: W = W8; break;
    default: W = W9; break;
  }
  uint16_t* dst = WT + (size_t)blockIdx.z * 1048576;
  const int n0 = blockIdx.x * 32, k0 = blockIdx.y * 32;
#pragma unroll
  for (int i = 0; i < 32; i += 8)
    tl[ty + i][tx] = W[(size_t)(k0 + ty + i) * 1024 + n0 + tx];
  __syncthreads();
#pragma unroll
  for (int i = 0; i < 32; i += 8)
    dst[(size_t)(n0 + ty + i) * 1024 + k0 + tx] = f2b(tl[tx][ty + i]);
}

// ---------------- merged projection GEMM (qkv + side0 + side1), 896 blocks ----
// XOR-swizzled row-major LDS (0 conflicts), BK=64 (32 MFMA per barrier-pair),
// 2 buffers (64 KB -> 2 blocks/CU): stage tile i+1, vmcnt(8) waits only for
// tile i's loads (the fresh 8 stay in flight across the compute).
__global__ __launch_bounds__(256) void proj_k(
    const uint16_t* __restrict__ xb, const uint16_t* __restrict__ sdb,
    const uint16_t* __restrict__ WT, const float* __restrict__ biasc,
    uint16_t* __restrict__ qkv, uint16_t* __restrict__ sqk0,
    uint16_t* __restrict__ sqk1, uint16_t* __restrict__ vT) {
  __shared__ uint16_t As[2][8192];
  __shared__ uint16_t Bs[2][8192];
  const int bid = blockIdx.x;
  const uint16_t* A; const uint16_t* BT; const float* bias; uint16_t* C;
  int lda, ldc, bx, by;
  bool dovt = false;
  if (bid < 384) {
    bx = bid % 24; by = bid / 24;
    A = xb; lda = 1024; BT = WT; bias = biasc; C = qkv; ldc = 3072;
    dovt = bx >= 16;
  } else if (bid < 640) {
    int r = bid - 384; bx = r & 15; by = r >> 4;
    A = sdb; lda = 2048; BT = WT + 3145728; bias = biasc + 3072;
    C = sqk0; ldc = 2048;
  } else {
    int r = bid - 640; bx = r & 15; by = r >> 4;
    A = sdb + 1024; lda = 2048; BT = WT + 5242880; bias = biasc + 5120;
    C = sqk1; ldc = 2048;
  }
  const int t = threadIdx.x;
  const int lane = t & 63, w = t >> 6;
  const int wr = w >> 1, wc = w & 1;
  const int l15 = lane & 15, g = lane >> 4;
  const int bm0 = by * 128, bn0 = bx * 128;

  const int scol = ((t & 3) ^ ((t >> 3) & 3)) * 8;
  const uint16_t* ga = A  + (size_t)(bm0 + (t >> 2)) * lda  + scol;
  const uint16_t* gb = BT + (size_t)(bn0 + (t >> 2)) * 1024 + scol;
  const int gsw = (g ^ ((l15 >> 1) & 3)) * 8;

#define GSTAGE(bufi, k0) do { \
    GLDS16(ga + (k0),                          &As[bufi][t * 8]); \
    GLDS16(ga + (size_t)64 * lda + (k0),       &As[bufi][2048 + t * 8]); \
    GLDS16(ga + (k0) + 32,                     &As[bufi][4096 + t * 8]); \
    GLDS16(ga + (size_t)64 * lda + (k0) + 32,  &As[bufi][6144 + t * 8]); \
    GLDS16(gb + (k0),                          &Bs[bufi][t * 8]); \
    GLDS16(gb + 64 * 1024 + (k0),              &Bs[bufi][2048 + t * 8]); \
    GLDS16(gb + (k0) + 32,                     &Bs[bufi][4096 + t * 8]); \
    GLDS16(gb + 64 * 1024 + (k0) + 32,         &Bs[bufi][6144 + t * 8]); } while (0)

  f32x4 acc[4][4] = {};
  GSTAGE(0, 0);
  int cur = 0;
  for (int it = 0; it < 16; it++) {
    if (it < 15) { GSTAGE(cur ^ 1, (it + 1) * 64); WAITVM(8); }
    else WAITVM(0);
    BAR();
#pragma unroll
    for (int hf = 0; hf < 2; hf++) {
      const int ho = hf * 4096;
      bf16x8 af[4], bf[4];
#pragma unroll
      for (int i = 0; i < 4; i++)
        af[i] = *(const bf16x8*)&As[cur][ho + (wr * 64 + i * 16 + l15) * 32 + gsw];
#pragma unroll
      for (int i = 0; i < 4; i++)
        bf[i] = *(const bf16x8*)&Bs[cur][ho + (wc * 64 + i * 16 + l15) * 32 + gsw];
#pragma unroll
      for (int mi = 0; mi < 4; mi++)
#pragma unroll
        for (int ni = 0; ni < 4; ni++)
          acc[mi][ni] = mfma32(af[mi], bf[ni], acc[mi][ni]);
    }
    WAITLGKM0;
    BAR();
    cur ^= 1;
  }
#undef GSTAGE

#pragma unroll
  for (int mi = 0; mi < 4; mi++) {
#pragma unroll
    for (int ni = 0; ni < 4; ni++) {
      const int row0 = bm0 + wr * 64 + mi * 16 + g * 4;
      const int col  = bn0 + wc * 64 + ni * 16 + l15;
      const float bc = bias[col];
      u16x4 ov;
#pragma unroll
      for (int r = 0; r < 4; r++) {
        float v = acc[mi][ni][r] + bc;
        ov[r] = f2b(v);
        C[(size_t)(row0 + r) * ldc + col] = ov[r];
      }
      if (dovt) {
        const int cc = col - 2048, hh = cc >> 6, dd = cc & 63;
        const int bb = row0 >> 10, s0 = row0 & 1023;
        *(u16x4*)&vT[((size_t)((bb * 16 + hh) * 64 + dd)) * 1024 + s0] = ov;
      }
    }
  }
}

// ---------------- GEMM 64x64 (512 blocks; BK=64 super-iters; 2-deep) ----
enum { EPI_BF16 = 0, EPI_RES = 1, EPI_GELU = 2 };

template<int EPI>
__global__ __launch_bounds__(256) void gemm64_k(
    const uint16_t* __restrict__ A, int lda,
    const uint16_t* __restrict__ BT,
    const float* __restrict__ bias,
    const float* __restrict__ res,
    void* __restrict__ Cv, int ldc) {
  __shared__ uint16_t As[3][4096];
  __shared__ uint16_t Bs[3][4096];
  const int t = threadIdx.x;
  const int lane = t & 63, w = t >> 6;
  const int wr = w >> 1, wc = w & 1;
  const int l15 = lane & 15, g = lane >> 4;
  const int bm0 = blockIdx.y * 64, bn0 = blockIdx.x * 64;

  const int scol = ((t & 3) ^ ((t >> 3) & 3)) * 8;
  const uint16_t* ga = A  + (size_t)(bm0 + (t >> 2)) * lda  + scol;
  const uint16_t* gb = BT + (size_t)(bn0 + (t >> 2)) * 1024 + scol;
  const int gsw = (g ^ ((l15 >> 1) & 3)) * 8;

#define GSTAGE64(bufi, k0) do { \
    GLDS16(ga + (k0),      &As[bufi][t * 8]); \
    GLDS16(ga + (k0) + 32, &As[bufi][2048 + t * 8]); \
    GLDS16(gb + (k0),      &Bs[bufi][t * 8]); \
    GLDS16(gb + (k0) + 32, &Bs[bufi][2048 + t * 8]); } while (0)

  f32x4 acc[2][2] = {};
  GSTAGE64(0, 0);
  GSTAGE64(1, 64);
  int cur = 0;
  for (int it = 0; it < 16; it++) {
    if (it < 14) {
      int pre = cur + 2; if (pre >= 3) pre -= 3;
      GSTAGE64(pre, (it + 2) * 64);
      WAITVM(8);
    } else if (it == 14) {
      WAITVM(4);
    } else {
      WAITVM(0);
    }
    BAR();
#pragma unroll
    for (int hf = 0; hf < 2; hf++) {
      const int ho = hf * 2048;
      bf16x8 af[2], bf[2];
#pragma unroll
      for (int i = 0; i < 2; i++)
        af[i] = *(const bf16x8*)&As[cur][ho + (wr * 32 + i * 16 + l15) * 32 + gsw];
#pragma unroll
      for (int i = 0; i < 2; i++)
        bf[i] = *(const bf16x8*)&Bs[cur][ho + (wc * 32 + i * 16 + l15) * 32 + gsw];
#pragma unroll
      for (int mi = 0; mi < 2; mi++)
#pragma unroll
        for (int ni = 0; ni < 2; ni++)
          acc[mi][ni] = mfma32(af[mi], bf[ni], acc[mi][ni]);
    }
    WAITLGKM0;
    BAR();
    cur = (cur + 1 == 3) ? 0 : cur + 1;
  }
#undef GSTAGE64

#pragma unroll
  for (int mi = 0; mi < 2; mi++) {
#pragma unroll
    for (int ni = 0; ni < 2; ni++) {
      const int row0 = bm0 + wr * 32 + mi * 16 + g * 4;
      const int col  = bn0 + wc * 32 + ni * 16 + l15;
      const float bc = bias[col];
#pragma unroll
      for (int r = 0; r < 4; r++) {
        float v = acc[mi][ni][r] + bc;
        const size_t idx = (size_t)(row0 + r) * ldc + col;
        if constexpr (EPI == EPI_RES) {
          ((float*)Cv)[idx] = v + res[idx];
        } else if constexpr (EPI == EPI_GELU) {
          float gl = 0.5f * v * (1.0f + erff(v * 0.70710678118654752f));
          ((uint16_t*)Cv)[idx] = f2b(gl);
        } else {
          ((uint16_t*)Cv)[idx] = f2b(v);
        }
      }
    }
  }
}

// ---------------- attention pass 1: Z partials (k-split, 3-buffer 2-deep) ----
__global__ __launch_bounds__(256) void attn_z(
    const uint16_t* __restrict__ qkv,
    const uint16_t* __restrict__ sqk0,
    const uint16_t* __restrict__ sqk1,
    float* __restrict__ zp) {
  __shared__ uint16_t Ks0[3][2048];
  __shared__ uint16_t Ks1[3][2048];
  __shared__ uint16_t Ks2[3][2048];
  const int t = threadIdx.x;
  const int lane = t & 63, w = t >> 6;
  const int l15 = lane & 15, g = lane >> 4;
  const int bid = blockIdx.x;
  const int xcd = bid & 7, idx = bid >> 3;
  const int grp = xcd * 8 + (idx >> 4);
  const int qt = idx & 15;
  const int hb = grp >> 1, kc = grp & 1;
  const int b = hb >> 4, h = hb & 15;
  const int q0 = qt * 64 + w * 16;
  const float scl2 = 0.03125f * 1.44269504088896f;
  const size_t rq = (size_t)(b * 1024 + q0 + l15);

  bf16x8 qf[3][2];
  {
    const uint16_t* p = qkv + rq * 3072 + h * 64 + g * 8;
    qf[0][0] = *(const bf16x8*)p; qf[0][1] = *(const bf16x8*)(p + 32);
    p = sqk0 + rq * 2048 + h * 64 + g * 8;
    qf[1][0] = *(const bf16x8*)p; qf[1][1] = *(const bf16x8*)(p + 32);
    p = sqk1 + rq * 2048 + h * 64 + g * 8;
    qf[2][0] = *(const bf16x8*)p; qf[2][1] = *(const bf16x8*)(p + 32);
  }

  const int p_   = t & 15;
  const int gg_  = (t >> 4) & 3;
  const int hf_  = (t >> 6) & 1;
  const int stq_ = t >> 7;
  const int srow   = (p_ >> 2) * 8 + stq_ * 4 + (p_ & 3) + kc * 512;
  const int kcolel = hf_ * 32 + gg_ * 8;

  const uint16_t* pk0 = qkv  + (size_t)b * 1024 * 3072 + 1024 + h * 64
                      + (size_t)srow * 3072 + kcolel;
  const uint16_t* pk1 = sqk0 + (size_t)b * 1024 * 2048 + 1024 + h * 64
                      + (size_t)srow * 2048 + kcolel;
  const uint16_t* pk2 = sqk1 + (size_t)b * 1024 * 2048 + 1024 + h * 64
                      + (size_t)srow * 2048 + kcolel;

#define STAGE3(bufi) do { \
    GLDS16(pk0, &Ks0[bufi][t * 8]); \
    GLDS16(pk1, &Ks1[bufi][t * 8]); \
    GLDS16(pk2, &Ks2[bufi][t * 8]); \
    pk0 += 32 * 3072; pk1 += 32 * 2048; pk2 += 32 * 2048; } while (0)

  float z0 = 0.f, z1 = 0.f, z2 = 0.f;
  STAGE3(0);
  STAGE3(1);
  int cur = 0;
  for (int kt = 0; kt < 16; kt++) {
    if (kt < 14) {
      int pre = cur + 2; if (pre >= 3) pre -= 3;
      STAGE3(pre);
      WAITVM(6);
    } else if (kt == 14) {
      WAITVM(3);
    } else {
      WAITVM(0);
    }
    BAR();
#pragma unroll
    for (int st = 0; st < 2; st++) {
      f32x4 c0 = {}, c1 = {}, c2 = {};
      c0 = mfma32(*(const bf16x8*)&Ks0[cur][st * 1024 + lane * 8],       qf[0][0], c0);
      c0 = mfma32(*(const bf16x8*)&Ks0[cur][st * 1024 + 512 + lane * 8], qf[0][1], c0);
      c1 = mfma32(*(const bf16x8*)&Ks1[cur][st * 1024 + lane * 8],       qf[1][0], c1);
      c1 = mfma32(*(const bf16x8*)&Ks1[cur][st * 1024 + 512 + lane * 8], qf[1][1], c1);
      c2 = mfma32(*(const bf16x8*)&Ks2[cur][st * 1024 + lane * 8],       qf[2][0], c2);
      c2 = mfma32(*(const bf16x8*)&Ks2[cur][st * 1024 + 512 + lane * 8], qf[2][1], c2);
#pragma unroll
      for (int r = 0; r < 4; r++) {
        z0 += __builtin_amdgcn_exp2f(c0[r] * scl2);
        z1 += __builtin_amdgcn_exp2f(c1[r] * scl2);
        z2 += __builtin_amdgcn_exp2f(c2[r] * scl2);
      }
    }
    WAITLGKM0;
    BAR();
    cur = (cur + 1 == 3) ? 0 : cur + 1;
  }
#undef STAGE3
  z0 += __shfl_xor(z0, 16, 64); z0 += __shfl_xor(z0, 32, 64);
  z1 += __shfl_xor(z1, 16, 64); z1 += __shfl_xor(z1, 32, 64);
  z2 += __shfl_xor(z2, 16, 64); z2 += __shfl_xor(z2, 32, 64);
  if (lane < 16) {
    const int qi = hb * 1024 + q0 + l15;
    zp[kc * 32768 + qi]          = z0;
    zp[65536 + kc * 32768 + qi]  = z1;
    zp[131072 + kc * 32768 + qi] = z2;
  }
}

// ---------------- attention pass 2 (zred inlined): partial O ----------------
__global__ __launch_bounds__(256) void attn_o(
    const uint16_t* __restrict__ qkv,
    const uint16_t* __restrict__ sqk0,
    const uint16_t* __restrict__ sqk1,
    const uint16_t* __restrict__ vT,
    const float* __restrict__ zp,
    uint16_t* __restrict__ op) {
  __shared__ uint16_t Ks0[2][2048];
  __shared__ uint16_t Ks1[2][2048];
  __shared__ uint16_t Ks2[2][2048];
  __shared__ uint16_t Vs[2][2048];
  const int t = threadIdx.x;
  const int lane = t & 63, w = t >> 6;
  const int l15 = lane & 15, g = lane >> 4;
  const int bid = blockIdx.x;
  const int xcd = bid & 7, idx = bid >> 3;
  const int grp = xcd * 8 + (idx >> 4);
  const int qt = idx & 15;
  const int hb = grp >> 1, kc = grp & 1;
  const int b = hb >> 4, h = hb & 15;
  const int q0 = qt * 64 + w * 16;
  const float scl2 = 0.03125f * 1.44269504088896f;
  const size_t rq = (size_t)(b * 1024 + q0 + l15);

  bf16x8 qf[3][2];
  {
    const uint16_t* p = qkv + rq * 3072 + h * 64 + g * 8;
    qf[0][0] = *(const bf16x8*)p; qf[0][1] = *(const bf16x8*)(p + 32);
    p = sqk0 + rq * 2048 + h * 64 + g * 8;
    qf[1][0] = *(const bf16x8*)p; qf[1][1] = *(const bf16x8*)(p + 32);
    p = sqk1 + rq * 2048 + h * 64 + g * 8;
    qf[2][0] = *(const bf16x8*)p; qf[2][1] = *(const bf16x8*)(p + 32);
  }
  const int qi = hb * 1024 + q0 + l15;
  const float lz0 = __builtin_amdgcn_logf(zp[qi] + zp[qi + 32768]);
  const float lz1 = __builtin_amdgcn_logf(zp[qi + 65536] + zp[qi + 98304]);
  const float lz2 = __builtin_amdgcn_logf(zp[qi + 131072] + zp[qi + 163840]);

  const int p_   = t & 15;
  const int gg_  = (t >> 4) & 3;
  const int hf_  = (t >> 6) & 1;
  const int stq_ = t >> 7;
  const int srow   = (p_ >> 2) * 8 + stq_ * 4 + (p_ & 3) + kc * 512;
  const int kcolel = hf_ * 32 + gg_ * 8;

  const uint16_t* pk0 = qkv  + (size_t)b * 1024 * 3072 + 1024 + h * 64
                      + (size_t)srow * 3072 + kcolel;
  const uint16_t* pk1 = sqk0 + (size_t)b * 1024 * 2048 + 1024 + h * 64
                      + (size_t)srow * 2048 + kcolel;
  const uint16_t* pk2 = sqk1 + (size_t)b * 1024 * 2048 + 1024 + h * 64
                      + (size_t)srow * 2048 + kcolel;
  const uint16_t* pv  = vT + ((size_t)hb * 64 + (t >> 6) * 16 + p_) * 1024
                      + kc * 512 + gg_ * 8;

#define STAGE4(bufi) do { \
    GLDS16(pk0, &Ks0[bufi][t * 8]); \
    GLDS16(pk1, &Ks1[bufi][t * 8]); \
    GLDS16(pk2, &Ks2[bufi][t * 8]); \
    GLDS16(pv,  &Vs[bufi][t * 8]); \
    pk0 += 32 * 3072; pk1 += 32 * 2048; pk2 += 32 * 2048; pv += 32; } while (0)

  f32x4 accO[4] = {};
  int cur = 0;
  STAGE4(0);
  for (int kt = 0; kt < 16; kt++) {
    if (kt < 15) { STAGE4(cur ^ 1); WAITVM(4); }
    else WAITVM(0);
    BAR();
    u16x8 pu;
#pragma unroll
    for (int sub = 0; sub < 2; sub++) {
      f32x4 c0 = {}, c1 = {}, c2 = {};
      c0 = mfma32(*(const bf16x8*)&Ks0[cur][sub * 1024 + lane * 8],       qf[0][0], c0);
      c0 = mfma32(*(const bf16x8*)&Ks0[cur][sub * 1024 + 512 + lane * 8], qf[0][1], c0);
      c1 = mfma32(*(const bf16x8*)&Ks1[cur][sub * 1024 + lane * 8],       qf[1][0], c1);
      c1 = mfma32(*(const bf16x8*)&Ks1[cur][sub * 1024 + 512 + lane * 8], qf[1][1], c1);
      c2 = mfma32(*(const bf16x8*)&Ks2[cur][sub * 1024 + lane * 8],       qf[2][0], c2);
      c2 = mfma32(*(const bf16x8*)&Ks2[cur][sub * 1024 + 512 + lane * 8], qf[2][1], c2);
#pragma unroll
      for (int r = 0; r < 4; r++) {
        float m = fmaxf(fmaxf(c0[r] * scl2 - lz0, c1[r] * scl2 - lz1),
                        c2[r] * scl2 - lz2);
        pu[sub * 4 + r] = f2b(__builtin_amdgcn_exp2f(m));
      }
    }
    const bf16x8 pf = __builtin_bit_cast(bf16x8, pu);
#pragma unroll
    for (int dt = 0; dt < 4; dt++) {
      bf16x8 vf = *(const bf16x8*)&Vs[cur][dt * 512 + lane * 8];
      accO[dt] = mfma32(vf, pf, accO[dt]);
    }
    WAITLGKM0;
    BAR();
    cur ^= 1;
  }
#undef STAGE4

  uint16_t* ob = op + (size_t)kc * 2097152 + rq * 1024 + h * 64;
#pragma unroll
  for (int dt = 0; dt < 4; dt++) {
    u16x4 o4;
#pragma unroll
    for (int r = 0; r < 4; r++) o4[r] = f2b(accO[dt][r]);
    *(u16x4*)(ob + dt * 16 + g * 4) = o4;
  }
}

// ---------------- O partial reduce: Ob = bf16(op0 + op1) ----------------
__global__ __launch_bounds__(256) void ored_k(const uint16_t* __restrict__ op0,
                                              const uint16_t* __restrict__ op1,
                                              uint16_t* __restrict__ Ob) {
  int i = (blockIdx.x * 256 + threadIdx.x) * 4;
  u16x4 a = *(const u16x4*)(op0 + i);
  u16x4 b = *(const u16x4*)(op1 + i);
  u16x4 o;
#pragma unroll
  for (int j = 0; j < 4; j++) o[j] = f2b(b2f(a[j]) + b2f(b[j]));
  *(u16x4*)(Ob + i) = o;
}

// ---------------- LayerNorm over rows of 1024 fp32, optional bf16 copy ----------------
template<int WB>
__global__ __launch_bounds__(256) void ln_k(const float* __restrict__ X,
                                            const float* __restrict__ G,
                                            const float* __restrict__ Bt,
                                            float* __restrict__ Yf,
                                            uint16_t* __restrict__ Yb) {
  const int row = blockIdx.x, t = threadIdx.x;
  const int lane = t & 63, w = t >> 6;
  const size_t base = (size_t)row * 1024 + t * 4;
  f32x4 x = *(const f32x4*)(X + base);
  float s  = x[0] + x[1] + x[2] + x[3];
  float s2 = x[0] * x[0] + x[1] * x[1] + x[2] * x[2] + x[3] * x[3];
#pragma unroll
  for (int o = 1; o < 64; o <<= 1) {
    s  += __shfl_xor(s,  o, 64);
    s2 += __shfl_xor(s2, o, 64);
  }
  __shared__ float red[8];
  if (lane == 0) { red[w] = s; red[4 + w] = s2; }
  __syncthreads();
  s  = red[0] + red[1] + red[2] + red[3];
  s2 = red[4] + red[5] + red[6] + red[7];
  const float mean = s * (1.0f / 1024.0f);
  const float rstd = rsqrtf(s2 * (1.0f / 1024.0f) - mean * mean + 1e-5f);
  f32x4 gv = *(const f32x4*)(G + t * 4);
  f32x4 bv = *(const f32x4*)(Bt + t * 4);
  f32x4 y;
#pragma unroll
  for (int i = 0; i < 4; i++) y[i] = (x[i] - mean) * rstd * gv[i] + bv[i];
  *(f32x4*)(Yf + base) = y;
  if constexpr (WB) {
    u16x4 o;
#pragma unroll
    for (int i = 0; i < 4; i++) o[i] = f2b(y[i]);
    *(u16x4*)(Yb + base) = o;
  }
}

// ---------------- host ----------------
extern "C" void kernel_launch(void* const* d_in, const int* in_sizes, int n_in,
                              void* d_out, int out_size, void* d_ws, size_t ws_size,
                              hipStream_t stream) {
  (void)in_sizes; (void)n_in; (void)out_size;
  const float* id_x = (const float*)d_in[0];
  const float* side = (const float*)d_in[1];
  const float* Wq  = (const float*)d_in[3];
  const float* bq  = (const float*)d_in[4];
  const float* Wk  = (const float*)d_in[5];
  const float* bk  = (const float*)d_in[6];
  const float* Wv  = (const float*)d_in[7];
  const float* bv  = (const float*)d_in[8];
  const float* sWq = (const float*)d_in[9];
  const float* sbq = (const float*)d_in[10];
  const float* sWk = (const float*)d_in[11];
  const float* sbk = (const float*)d_in[12];
  const float* Wo  = (const float*)d_in[13];
  const float* bo  = (const float*)d_in[14];
  const float* W1  = (const float*)d_in[15];
  const float* b1  = (const float*)d_in[16];
  const float* W2  = (const float*)d_in[17];
  const float* b2  = (const float*)d_in[18];
  const float* g1  = (const float*)d_in[19];
  const float* be1 = (const float*)d_in[20];
  const float* g2  = (const float*)d_in[21];
  const float* be2 = (const float*)d_in[22];

  char* ws = (char*)d_ws;
  const size_t oWT   = 0;                       // 10x 1024x1024 bf16 = 20,971,520
  const size_t oBias = 20971520;                // 7168 f32 = 28,672
  const size_t oZP   = 21000192;                // 3*65536 f32 = 786,432
  const size_t oC    = 22179840;                // 4 MB: xb -> op0
  const size_t oD    = 26374144;                // 8 MB: sdb -> op1 | Ob
  const size_t oE    = 34762752;                // 32 MB
  const size_t total = oE + 33554432;           // 68,317,184
  if (ws_size < total) return;

  uint16_t* WT    = (uint16_t*)(ws + oWT);
  float*    biasc = (float*)(ws + oBias);
  float*    zp    = (float*)(ws + oZP);
  uint16_t* xb    = (uint16_t*)(ws + oC);
  uint16_t* op0   = (uint16_t*)(ws + oC);          // aliases xb (dead post-proj)
  uint16_t* sdb   = (uint16_t*)(ws + oD);
  uint16_t* Ob    = (uint16_t*)(ws + oD + 4194304);
  char* E = ws + oE;
  uint16_t* qkv  = (uint16_t*)(E);                  // 12 MB
  uint16_t* sqk0 = (uint16_t*)(E + 12582912);       // 8 MB
  uint16_t* sqk1 = (uint16_t*)(E + 20971520);       // 8 MB
  uint16_t* vTp  = (uint16_t*)(E + 29360128);       // 4 MB
  // post-attention aliases (qkv/sqk/vT dead after attn_o):
  float*    x1   = (float*)(E);                     // 8 MB
  float*    x1n  = (float*)(E + 8388608);           // 8 MB
  uint16_t* x1nb = (uint16_t*)(E + 16777216);       // 4 MB
  uint16_t* hb   = (uint16_t*)(E + 20971520);       // 4 MB
  float*    x2   = (float*)(E + 25165824);          // 8 MB

  wtrans_all<<<dim3(32, 32, 17), dim3(32, 8), 0, stream>>>(
      Wq, Wk, Wv, sWq, sWk, sWq + 1048576, sWk + 1048576, Wo, W1, W2, WT,
      bq, bk, bv, sbq, sbk, biasc, id_x, side, xb, sdb);

  proj_k<<<896, 256, 0, stream>>>(xb, sdb, WT, biasc, qkv, sqk0, sqk1, vTp);

  attn_z<<<1024, 256, 0, stream>>>(qkv, sqk0, sqk1, zp);
  attn_o<<<1024, 256, 0, stream>>>(qkv, sqk0, sqk1, vTp, zp, op0);
  ored_k<<<2048, 256, 0, stream>>>(op0, op0 + 2097152, Ob);

  gemm64_k<EPI_RES><<<dim3(16, 32), 256, 0, stream>>>(Ob, 1024, WT + 7340032, bo, id_x, x1, 1024);
  ln_k<1><<<2048, 256, 0, stream>>>(x1, g1, be1, x1n, x1nb);
  gemm64_k<EPI_GELU><<<dim3(16, 32), 256, 0, stream>>>(x1nb, 1024, WT + 8388608, b1, nullptr, hb, 1024);
  gemm64_k<EPI_RES><<<dim3(16, 32), 256, 0, stream>>>(hb, 1024, WT + 9437184, b2, x1n, x2, 1024);
  ln_k<0><<<2048, 256, 0, stream>>>(x2, g2, be2, (float*)d_out, nullptr);
}

// Round 12
// 183.547 us; speedup vs baseline: 1.1470x; 1.0007x over previous
//
#include <hip/hip_runtime.h>
#include <hip/hip_bf16.h>
#include <stdint.h>

typedef float   f32x4  __attribute__((ext_vector_type(4)));
typedef __bf16  bf16x8 __attribute__((ext_vector_type(8)));
typedef unsigned short u16x4 __attribute__((ext_vector_type(4)));
typedef unsigned short u16x8 __attribute__((ext_vector_type(8)));

__device__ __forceinline__ uint16_t f2b(float x) {
  union { float f; uint32_t u; } c; c.f = x;
  uint32_t u = c.u;
  return (uint16_t)((u + 0x7FFFu + ((u >> 16) & 1u)) >> 16);
}
__device__ __forceinline__ float b2f(uint16_t x) {
  union { uint32_t u; float f; } c; c.u = ((uint32_t)x) << 16;
  return c.f;
}

__device__ __forceinline__ f32x4 mfma32(bf16x8 a, bf16x8 b, f32x4 c) {
  return __builtin_amdgcn_mfma_f32_16x16x32_bf16(a, b, c, 0, 0, 0);
}

#define GLDS16(g, l) __builtin_amdgcn_global_load_lds( \
    (const __attribute__((address_space(1))) void*)(const void*)(g), \
    (__attribute__((address_space(3))) void*)(void*)(l), 16, 0, 0)

#define WAITVM(N) asm volatile("s_waitcnt vmcnt(" #N ")" ::: "memory")
#define WAITLGKM0 asm volatile("s_waitcnt lgkmcnt(0)" ::: "memory")
#define BAR() __builtin_amdgcn_s_barrier()

// -------- weight transposes + bias concat (z=10) + fp32->bf16 (z=11..16) ----
__global__ __launch_bounds__(256) void wtrans_all(
    const float* __restrict__ W0, const float* __restrict__ W1,
    const float* __restrict__ W2, const float* __restrict__ W3,
    const float* __restrict__ W4, const float* __restrict__ W5,
    const float* __restrict__ W6, const float* __restrict__ W7,
    const float* __restrict__ W8, const float* __restrict__ W9,
    uint16_t* __restrict__ WT,
    const float* __restrict__ bq, const float* __restrict__ bk,
    const float* __restrict__ bv, const float* __restrict__ sbq,
    const float* __restrict__ sbk, float* __restrict__ biasc,
    const float* __restrict__ id_x, const float* __restrict__ side,
    uint16_t* __restrict__ xb, uint16_t* __restrict__ sdb) {
  __shared__ float tl[32][33];
  const int tx = threadIdx.x, ty = threadIdx.y; // (32, 8)
  if (blockIdx.z >= 11) {
    size_t zi = blockIdx.z - 11;
    size_t base = ((zi * 1024 + blockIdx.y * 32 + blockIdx.x) * 256
                   + ty * 32 + tx) * 4;
    const float* in; uint16_t* out;
    if (base < 2097152) { in = id_x; out = xb; }
    else { in = side; out = sdb; base -= 2097152; }
    f32x4 v = *(const f32x4*)(in + base);
    u16x4 o;
    o[0] = f2b(v[0]); o[1] = f2b(v[1]); o[2] = f2b(v[2]); o[3] = f2b(v[3]);
    *(u16x4*)(out + base) = o;
    return;
  }
  if (blockIdx.z == 10) {
    int i = (blockIdx.y * 32 + blockIdx.x) * 256 + ty * 32 + tx;
    if (i < 7168) {
      int seg = i >> 10, off = i & 1023;
      float v;
      switch (seg) {
        case 0: v = bq[off]; break;
        case 1: v = bk[off]; break;
        case 2: v = bv[off]; break;
        case 3: v = sbq[off]; break;
        case 4: v = sbk[off]; break;
        case 5: v = sbq[1024 + off]; break;
        default: v = sbk[1024 + off]; break;
      }
      biasc[i] = v;
    }
    return;
  }
  const float* W;
  switch (blockIdx.z) {
    case 0: W = W0; break; case 1: W = W1; break; case 2: W = W2; break;
    case 3: W = W3; break; case 4: W = W4; break; case 5: W = W5; break;
    case 6: W = W6; break; case 7: W = W7; break; case 8: W = W8; break;
    default: W = W9; break;
  }
  uint16_t* dst = WT + (size_t)blockIdx.z * 1048576;
  const int n0 = blockIdx.x * 32, k0 = blockIdx.y * 32;
#pragma unroll
  for (int i = 0; i < 32; i += 8)
    tl[ty + i][tx] = W[(size_t)(k0 + ty + i) * 1024 + n0 + tx];
  __syncthreads();
#pragma unroll
  for (int i = 0; i < 32; i += 8)
    dst[(size_t)(n0 + ty + i) * 1024 + k0 + tx] = f2b(tl[tx][ty + i]);
}

// ---------------- merged projection GEMM (qkv + side0 + side1), 896 blocks ----
// XOR-swizzled row-major LDS (0 conflicts), BK=64, 2 buffers (64 KB, 2 blk/CU).
// bx-grouped XCD map: XCD k owns B-panels bx in {3k..3k+2} (qkv) / {2k,2k+1}
// (sides) -> per-XCD B footprint 1.75 MB, L2-resident; A streams via L3.
__global__ __launch_bounds__(256) void proj_k(
    const uint16_t* __restrict__ xb, const uint16_t* __restrict__ sdb,
    const uint16_t* __restrict__ WT, const float* __restrict__ biasc,
    uint16_t* __restrict__ qkv, uint16_t* __restrict__ sqk0,
    uint16_t* __restrict__ sqk1, uint16_t* __restrict__ vT) {
  __shared__ uint16_t As[2][8192];
  __shared__ uint16_t Bs[2][8192];
  const int xcd = blockIdx.x & 7, s = blockIdx.x >> 3;  // s in [0,112)
  const uint16_t* A; const uint16_t* BT; const float* bias; uint16_t* C;
  int lda, ldc, bx, by;
  bool dovt = false;
  if (s < 48) {
    bx = xcd * 3 + s % 3; by = s / 3;
    A = xb; lda = 1024; BT = WT; bias = biasc; C = qkv; ldc = 3072;
    dovt = bx >= 16;
  } else if (s < 80) {
    int r = s - 48; bx = xcd * 2 + (r & 1); by = r >> 1;
    A = sdb; lda = 2048; BT = WT + 3145728; bias = biasc + 3072;
    C = sqk0; ldc = 2048;
  } else {
    int r = s - 80; bx = xcd * 2 + (r & 1); by = r >> 1;
    A = sdb + 1024; lda = 2048; BT = WT + 5242880; bias = biasc + 5120;
    C = sqk1; ldc = 2048;
  }
  const int t = threadIdx.x;
  const int lane = t & 63, w = t >> 6;
  const int wr = w >> 1, wc = w & 1;
  const int l15 = lane & 15, g = lane >> 4;
  const int bm0 = by * 128, bn0 = bx * 128;

  const int scol = ((t & 3) ^ ((t >> 3) & 3)) * 8;
  const uint16_t* ga = A  + (size_t)(bm0 + (t >> 2)) * lda  + scol;
  const uint16_t* gb = BT + (size_t)(bn0 + (t >> 2)) * 1024 + scol;
  const int gsw = (g ^ ((l15 >> 1) & 3)) * 8;

#define GSTAGE(bufi, k0) do { \
    GLDS16(ga + (k0),                          &As[bufi][t * 8]); \
    GLDS16(ga + (size_t)64 * lda + (k0),       &As[bufi][2048 + t * 8]); \
    GLDS16(ga + (k0) + 32,                     &As[bufi][4096 + t * 8]); \
    GLDS16(ga + (size_t)64 * lda + (k0) + 32,  &As[bufi][6144 + t * 8]); \
    GLDS16(gb + (k0),                          &Bs[bufi][t * 8]); \
    GLDS16(gb + 64 * 1024 + (k0),              &Bs[bufi][2048 + t * 8]); \
    GLDS16(gb + (k0) + 32,                     &Bs[bufi][4096 + t * 8]); \
    GLDS16(gb + 64 * 1024 + (k0) + 32,         &Bs[bufi][6144 + t * 8]); } while (0)

  f32x4 acc[4][4] = {};
  GSTAGE(0, 0);
  int cur = 0;
  for (int it = 0; it < 16; it++) {
    if (it < 15) { GSTAGE(cur ^ 1, (it + 1) * 64); WAITVM(8); }
    else WAITVM(0);
    BAR();
#pragma unroll
    for (int hf = 0; hf < 2; hf++) {
      const int ho = hf * 4096;
      bf16x8 af[4], bf[4];
#pragma unroll
      for (int i = 0; i < 4; i++)
        af[i] = *(const bf16x8*)&As[cur][ho + (wr * 64 + i * 16 + l15) * 32 + gsw];
#pragma unroll
      for (int i = 0; i < 4; i++)
        bf[i] = *(const bf16x8*)&Bs[cur][ho + (wc * 64 + i * 16 + l15) * 32 + gsw];
#pragma unroll
      for (int mi = 0; mi < 4; mi++)
#pragma unroll
        for (int ni = 0; ni < 4; ni++)
          acc[mi][ni] = mfma32(af[mi], bf[ni], acc[mi][ni]);
    }
    WAITLGKM0;
    BAR();
    cur ^= 1;
  }
#undef GSTAGE

#pragma unroll
  for (int mi = 0; mi < 4; mi++) {
#pragma unroll
    for (int ni = 0; ni < 4; ni++) {
      const int row0 = bm0 + wr * 64 + mi * 16 + g * 4;
      const int col  = bn0 + wc * 64 + ni * 16 + l15;
      const float bc = bias[col];
      u16x4 ov;
#pragma unroll
      for (int r = 0; r < 4; r++) {
        float v = acc[mi][ni][r] + bc;
        ov[r] = f2b(v);
        C[(size_t)(row0 + r) * ldc + col] = ov[r];
      }
      if (dovt) {
        const int cc = col - 2048, hh = cc >> 6, dd = cc & 63;
        const int bb = row0 >> 10, s0 = row0 & 1023;
        *(u16x4*)&vT[((size_t)((bb * 16 + hh) * 64 + dd)) * 1024 + s0] = ov;
      }
    }
  }
}

// ---------------- GEMM 64x64 (512 blocks; BK=64; 4-buffer single-barrier) ----
// Stage@i targets buffer (cur+2)&3, last read at iter i-2 (fenced by BAR@i-1);
// WAITVM before BAR gives the cross-wave tile-landing guarantee. One barrier
// per iteration, no trailing lgkm drain.
enum { EPI_BF16 = 0, EPI_RES = 1, EPI_GELU = 2 };

template<int EPI>
__global__ __launch_bounds__(256) void gemm64_k(
    const uint16_t* __restrict__ A, int lda,
    const uint16_t* __restrict__ BT,
    const float* __restrict__ bias,
    const float* __restrict__ res,
    void* __restrict__ Cv, int ldc) {
  __shared__ uint16_t As[4][4096];
  __shared__ uint16_t Bs[4][4096];
  const int t = threadIdx.x;
  const int lane = t & 63, w = t >> 6;
  const int wr = w >> 1, wc = w & 1;
  const int l15 = lane & 15, g = lane >> 4;
  const int bm0 = blockIdx.y * 64, bn0 = blockIdx.x * 64;

  const int scol = ((t & 3) ^ ((t >> 3) & 3)) * 8;
  const uint16_t* ga = A  + (size_t)(bm0 + (t >> 2)) * lda  + scol;
  const uint16_t* gb = BT + (size_t)(bn0 + (t >> 2)) * 1024 + scol;
  const int gsw = (g ^ ((l15 >> 1) & 3)) * 8;

#define GSTAGE64(bufi, k0) do { \
    GLDS16(ga + (k0),      &As[bufi][t * 8]); \
    GLDS16(ga + (k0) + 32, &As[bufi][2048 + t * 8]); \
    GLDS16(gb + (k0),      &Bs[bufi][t * 8]); \
    GLDS16(gb + (k0) + 32, &Bs[bufi][2048 + t * 8]); } while (0)

  f32x4 acc[2][2] = {};
  GSTAGE64(0, 0);
  GSTAGE64(1, 64);
  int cur = 0;
  for (int it = 0; it < 16; it++) {
    if (it < 14) {
      GSTAGE64((cur + 2) & 3, (it + 2) * 64);
      WAITVM(8);
    } else if (it == 14) {
      WAITVM(4);
    } else {
      WAITVM(0);
    }
    BAR();
#pragma unroll
    for (int hf = 0; hf < 2; hf++) {
      const int ho = hf * 2048;
      bf16x8 af[2], bf[2];
#pragma unroll
      for (int i = 0; i < 2; i++)
        af[i] = *(const bf16x8*)&As[cur][ho + (wr * 32 + i * 16 + l15) * 32 + gsw];
#pragma unroll
      for (int i = 0; i < 2; i++)
        bf[i] = *(const bf16x8*)&Bs[cur][ho + (wc * 32 + i * 16 + l15) * 32 + gsw];
#pragma unroll
      for (int mi = 0; mi < 2; mi++)
#pragma unroll
        for (int ni = 0; ni < 2; ni++)
          acc[mi][ni] = mfma32(af[mi], bf[ni], acc[mi][ni]);
    }
    cur = (cur + 1) & 3;
  }
#undef GSTAGE64

#pragma unroll
  for (int mi = 0; mi < 2; mi++) {
#pragma unroll
    for (int ni = 0; ni < 2; ni++) {
      const int row0 = bm0 + wr * 32 + mi * 16 + g * 4;
      const int col  = bn0 + wc * 32 + ni * 16 + l15;
      const float bc = bias[col];
#pragma unroll
      for (int r = 0; r < 4; r++) {
        float v = acc[mi][ni][r] + bc;
        const size_t idx = (size_t)(row0 + r) * ldc + col;
        if constexpr (EPI == EPI_RES) {
          ((float*)Cv)[idx] = v + res[idx];
        } else if constexpr (EPI == EPI_GELU) {
          float gl = 0.5f * v * (1.0f + erff(v * 0.70710678118654752f));
          ((uint16_t*)Cv)[idx] = f2b(gl);
        } else {
          ((uint16_t*)Cv)[idx] = f2b(v);
        }
      }
    }
  }
}

// ---------------- attention pass 1: Z partials (k-split, 3-buffer 2-deep) ----
__global__ __launch_bounds__(256) void attn_z(
    const uint16_t* __restrict__ qkv,
    const uint16_t* __restrict__ sqk0,
    const uint16_t* __restrict__ sqk1,
    float* __restrict__ zp) {
  __shared__ uint16_t Ks0[3][2048];
  __shared__ uint16_t Ks1[3][2048];
  __shared__ uint16_t Ks2[3][2048];
  const int t = threadIdx.x;
  const int lane = t & 63, w = t >> 6;
  const int l15 = lane & 15, g = lane >> 4;
  const int bid = blockIdx.x;
  const int xcd = bid & 7, idx = bid >> 3;
  const int grp = xcd * 8 + (idx >> 4);
  const int qt = idx & 15;
  const int hb = grp >> 1, kc = grp & 1;
  const int b = hb >> 4, h = hb & 15;
  const int q0 = qt * 64 + w * 16;
  const float scl2 = 0.03125f * 1.44269504088896f;
  const size_t rq = (size_t)(b * 1024 + q0 + l15);

  bf16x8 qf[3][2];
  {
    const uint16_t* p = qkv + rq * 3072 + h * 64 + g * 8;
    qf[0][0] = *(const bf16x8*)p; qf[0][1] = *(const bf16x8*)(p + 32);
    p = sqk0 + rq * 2048 + h * 64 + g * 8;
    qf[1][0] = *(const bf16x8*)p; qf[1][1] = *(const bf16x8*)(p + 32);
    p = sqk1 + rq * 2048 + h * 64 + g * 8;
    qf[2][0] = *(const bf16x8*)p; qf[2][1] = *(const bf16x8*)(p + 32);
  }

  const int p_   = t & 15;
  const int gg_  = (t >> 4) & 3;
  const int hf_  = (t >> 6) & 1;
  const int stq_ = t >> 7;
  const int srow   = (p_ >> 2) * 8 + stq_ * 4 + (p_ & 3) + kc * 512;
  const int kcolel = hf_ * 32 + gg_ * 8;

  const uint16_t* pk0 = qkv  + (size_t)b * 1024 * 3072 + 1024 + h * 64
                      + (size_t)srow * 3072 + kcolel;
  const uint16_t* pk1 = sqk0 + (size_t)b * 1024 * 2048 + 1024 + h * 64
                      + (size_t)srow * 2048 + kcolel;
  const uint16_t* pk2 = sqk1 + (size_t)b * 1024 * 2048 + 1024 + h * 64
                      + (size_t)srow * 2048 + kcolel;

#define STAGE3(bufi) do { \
    GLDS16(pk0, &Ks0[bufi][t * 8]); \
    GLDS16(pk1, &Ks1[bufi][t * 8]); \
    GLDS16(pk2, &Ks2[bufi][t * 8]); \
    pk0 += 32 * 3072; pk1 += 32 * 2048; pk2 += 32 * 2048; } while (0)

  float z0 = 0.f, z1 = 0.f, z2 = 0.f;
  STAGE3(0);
  STAGE3(1);
  int cur = 0;
  for (int kt = 0; kt < 16; kt++) {
    if (kt < 14) {
      int pre = cur + 2; if (pre >= 3) pre -= 3;
      STAGE3(pre);
      WAITVM(6);
    } else if (kt == 14) {
      WAITVM(3);
    } else {
      WAITVM(0);
    }
    BAR();
#pragma unroll
    for (int st = 0; st < 2; st++) {
      f32x4 c0 = {}, c1 = {}, c2 = {};
      c0 = mfma32(*(const bf16x8*)&Ks0[cur][st * 1024 + lane * 8],       qf[0][0], c0);
      c0 = mfma32(*(const bf16x8*)&Ks0[cur][st * 1024 + 512 + lane * 8], qf[0][1], c0);
      c1 = mfma32(*(const bf16x8*)&Ks1[cur][st * 1024 + lane * 8],       qf[1][0], c1);
      c1 = mfma32(*(const bf16x8*)&Ks1[cur][st * 1024 + 512 + lane * 8], qf[1][1], c1);
      c2 = mfma32(*(const bf16x8*)&Ks2[cur][st * 1024 + lane * 8],       qf[2][0], c2);
      c2 = mfma32(*(const bf16x8*)&Ks2[cur][st * 1024 + 512 + lane * 8], qf[2][1], c2);
#pragma unroll
      for (int r = 0; r < 4; r++) {
        z0 += __builtin_amdgcn_exp2f(c0[r] * scl2);
        z1 += __builtin_amdgcn_exp2f(c1[r] * scl2);
        z2 += __builtin_amdgcn_exp2f(c2[r] * scl2);
      }
    }
    WAITLGKM0;
    BAR();
    cur = (cur + 1 == 3) ? 0 : cur + 1;
  }
#undef STAGE3
  z0 += __shfl_xor(z0, 16, 64); z0 += __shfl_xor(z0, 32, 64);
  z1 += __shfl_xor(z1, 16, 64); z1 += __shfl_xor(z1, 32, 64);
  z2 += __shfl_xor(z2, 16, 64); z2 += __shfl_xor(z2, 32, 64);
  if (lane < 16) {
    const int qi = hb * 1024 + q0 + l15;
    zp[kc * 32768 + qi]          = z0;
    zp[65536 + kc * 32768 + qi]  = z1;
    zp[131072 + kc * 32768 + qi] = z2;
  }
}

// ---------------- attention pass 2 (zred inlined): partial O ----------------
__global__ __launch_bounds__(256) void attn_o(
    const uint16_t* __restrict__ qkv,
    const uint16_t* __restrict__ sqk0,
    const uint16_t* __restrict__ sqk1,
    const uint16_t* __restrict__ vT,
    const float* __restrict__ zp,
    uint16_t* __restrict__ op) {
  __shared__ uint16_t Ks0[2][2048];
  __shared__ uint16_t Ks1[2][2048];
  __shared__ uint16_t Ks2[2][2048];
  __shared__ uint16_t Vs[2][2048];
  const int t = threadIdx.x;
  const int lane = t & 63, w = t >> 6;
  const int l15 = lane & 15, g = lane >> 4;
  const int bid = blockIdx.x;
  const int xcd = bid & 7, idx = bid >> 3;
  const int grp = xcd * 8 + (idx >> 4);
  const int qt = idx & 15;
  const int hb = grp >> 1, kc = grp & 1;
  const int b = hb >> 4, h = hb & 15;
  const int q0 = qt * 64 + w * 16;
  const float scl2 = 0.03125f * 1.44269504088896f;
  const size_t rq = (size_t)(b * 1024 + q0 + l15);

  bf16x8 qf[3][2];
  {
    const uint16_t* p = qkv + rq * 3072 + h * 64 + g * 8;
    qf[0][0] = *(const bf16x8*)p; qf[0][1] = *(const bf16x8*)(p + 32);
    p = sqk0 + rq * 2048 + h * 64 + g * 8;
    qf[1][0] = *(const bf16x8*)p; qf[1][1] = *(const bf16x8*)(p + 32);
    p = sqk1 + rq * 2048 + h * 64 + g * 8;
    qf[2][0] = *(const bf16x8*)p; qf[2][1] = *(const bf16x8*)(p + 32);
  }
  const int qi = hb * 1024 + q0 + l15;
  const float lz0 = __builtin_amdgcn_logf(zp[qi] + zp[qi + 32768]);
  const float lz1 = __builtin_amdgcn_logf(zp[qi + 65536] + zp[qi + 98304]);
  const float lz2 = __builtin_amdgcn_logf(zp[qi + 131072] + zp[qi + 163840]);

  const int p_   = t & 15;
  const int gg_  = (t >> 4) & 3;
  const int hf_  = (t >> 6) & 1;
  const int stq_ = t >> 7;
  const int srow   = (p_ >> 2) * 8 + stq_ * 4 + (p_ & 3) + kc * 512;
  const int kcolel = hf_ * 32 + gg_ * 8;

  const uint16_t* pk0 = qkv  + (size_t)b * 1024 * 3072 + 1024 + h * 64
                      + (size_t)srow * 3072 + kcolel;
  const uint16_t* pk1 = sqk0 + (size_t)b * 1024 * 2048 + 1024 + h * 64
                      + (size_t)srow * 2048 + kcolel;
  const uint16_t* pk2 = sqk1 + (size_t)b * 1024 * 2048 + 1024 + h * 64
                      + (size_t)srow * 2048 + kcolel;
  const uint16_t* pv  = vT + ((size_t)hb * 64 + (t >> 6) * 16 + p_) * 1024
                      + kc * 512 + gg_ * 8;

#define STAGE4(bufi) do { \
    GLDS16(pk0, &Ks0[bufi][t * 8]); \
    GLDS16(pk1, &Ks1[bufi][t * 8]); \
    GLDS16(pk2, &Ks2[bufi][t * 8]); \
    GLDS16(pv,  &Vs[bufi][t * 8]); \
    pk0 += 32 * 3072; pk1 += 32 * 2048; pk2 += 32 * 2048; pv += 32; } while (0)

  f32x4 accO[4] = {};
  int cur = 0;
  STAGE4(0);
  for (int kt = 0; kt < 16; kt++) {
    if (kt < 15) { STAGE4(cur ^ 1); WAITVM(4); }
    else WAITVM(0);
    BAR();
    u16x8 pu;
#pragma unroll
    for (int sub = 0; sub < 2; sub++) {
      f32x4 c0 = {}, c1 = {}, c2 = {};
      c0 = mfma32(*(const bf16x8*)&Ks0[cur][sub * 1024 + lane * 8],       qf[0][0], c0);
      c0 = mfma32(*(const bf16x8*)&Ks0[cur][sub * 1024 + 512 + lane * 8], qf[0][1], c0);
      c1 = mfma32(*(const bf16x8*)&Ks1[cur][sub * 1024 + lane * 8],       qf[1][0], c1);
      c1 = mfma32(*(const bf16x8*)&Ks1[cur][sub * 1024 + 512 + lane * 8], qf[1][1], c1);
      c2 = mfma32(*(const bf16x8*)&Ks2[cur][sub * 1024 + lane * 8],       qf[2][0], c2);
      c2 = mfma32(*(const bf16x8*)&Ks2[cur][sub * 1024 + 512 + lane * 8], qf[2][1], c2);
#pragma unroll
      for (int r = 0; r < 4; r++) {
        float m = fmaxf(fmaxf(c0[r] * scl2 - lz0, c1[r] * scl2 - lz1),
                        c2[r] * scl2 - lz2);
        pu[sub * 4 + r] = f2b(__builtin_amdgcn_exp2f(m));
      }
    }
    const bf16x8 pf = __builtin_bit_cast(bf16x8, pu);
#pragma unroll
    for (int dt = 0; dt < 4; dt++) {
      bf16x8 vf = *(const bf16x8*)&Vs[cur][dt * 512 + lane * 8];
      accO[dt] = mfma32(vf, pf, accO[dt]);
    }
    WAITLGKM0;
    BAR();
    cur ^= 1;
  }
#undef STAGE4

  uint16_t* ob = op + (size_t)kc * 2097152 + rq * 1024 + h * 64;
#pragma unroll
  for (int dt = 0; dt < 4; dt++) {
    u16x4 o4;
#pragma unroll
    for (int r = 0; r < 4; r++) o4[r] = f2b(accO[dt][r]);
    *(u16x4*)(ob + dt * 16 + g * 4) = o4;
  }
}

// ---------------- O partial reduce: Ob = bf16(op0 + op1) ----------------
__global__ __launch_bounds__(256) void ored_k(const uint16_t* __restrict__ op0,
                                              const uint16_t* __restrict__ op1,
                                              uint16_t* __restrict__ Ob) {
  int i = (blockIdx.x * 256 + threadIdx.x) * 4;
  u16x4 a = *(const u16x4*)(op0 + i);
  u16x4 b = *(const u16x4*)(op1 + i);
  u16x4 o;
#pragma unroll
  for (int j = 0; j < 4; j++) o[j] = f2b(b2f(a[j]) + b2f(b[j]));
  *(u16x4*)(Ob + i) = o;
}

// ---------------- LayerNorm over rows of 1024 fp32, optional bf16 copy ----------------
template<int WB>
__global__ __launch_bounds__(256) void ln_k(const float* __restrict__ X,
                                            const float* __restrict__ G,
                                            const float* __restrict__ Bt,
                                            float* __restrict__ Yf,
                                            uint16_t* __restrict__ Yb) {
  const int row = blockIdx.x, t = threadIdx.x;
  const int lane = t & 63, w = t >> 6;
  const size_t base = (size_t)row * 1024 + t * 4;
  f32x4 x = *(const f32x4*)(X + base);
  float s  = x[0] + x[1] + x[2] + x[3];
  float s2 = x[0] * x[0] + x[1] * x[1] + x[2] * x[2] + x[3] * x[3];
#pragma unroll
  for (int o = 1; o < 64; o <<= 1) {
    s  += __shfl_xor(s,  o, 64);
    s2 += __shfl_xor(s2, o, 64);
  }
  __shared__ float red[8];
  if (lane == 0) { red[w] = s; red[4 + w] = s2; }
  __syncthreads();
  s  = red[0] + red[1] + red[2] + red[3];
  s2 = red[4] + red[5] + red[6] + red[7];
  const float mean = s * (1.0f / 1024.0f);
  const float rstd = rsqrtf(s2 * (1.0f / 1024.0f) - mean * mean + 1e-5f);
  f32x4 gv = *(const f32x4*)(G + t * 4);
  f32x4 bv = *(const f32x4*)(Bt + t * 4);
  f32x4 y;
#pragma unroll
  for (int i = 0; i < 4; i++) y[i] = (x[i] - mean) * rstd * gv[i] + bv[i];
  *(f32x4*)(Yf + base) = y;
  if constexpr (WB) {
    u16x4 o;
#pragma unroll
    for (int i = 0; i < 4; i++) o[i] = f2b(y[i]);
    *(u16x4*)(Yb + base) = o;
  }
}

// ---------------- host ----------------
extern "C" void kernel_launch(void* const* d_in, const int* in_sizes, int n_in,
                              void* d_out, int out_size, void* d_ws, size_t ws_size,
                              hipStream_t stream) {
  (void)in_sizes; (void)n_in; (void)out_size;
  const float* id_x = (const float*)d_in[0];
  const float* side = (const float*)d_in[1];
  const float* Wq  = (const float*)d_in[3];
  const float* bq  = (const float*)d_in[4];
  const float* Wk  = (const float*)d_in[5];
  const float* bk  = (const float*)d_in[6];
  const float* Wv  = (const float*)d_in[7];
  const float* bv  = (const float*)d_in[8];
  const float* sWq = (const float*)d_in[9];
  const float* sbq = (const float*)d_in[10];
  const float* sWk = (const float*)d_in[11];
  const float* sbk = (const float*)d_in[12];
  const float* Wo  = (const float*)d_in[13];
  const float* bo  = (const float*)d_in[14];
  const float* W1  = (const float*)d_in[15];
  const float* b1  = (const float*)d_in[16];
  const float* W2  = (const float*)d_in[17];
  const float* b2  = (const float*)d_in[18];
  const float* g1  = (const float*)d_in[19];
  const float* be1 = (const float*)d_in[20];
  const float* g2  = (const float*)d_in[21];
  const float* be2 = (const float*)d_in[22];

  char* ws = (char*)d_ws;
  const size_t oWT   = 0;                       // 10x 1024x1024 bf16 = 20,971,520
  const size_t oBias = 20971520;                // 7168 f32 = 28,672
  const size_t oZP   = 21000192;                // 3*65536 f32 = 786,432
  const size_t oC    = 22179840;                // 4 MB: xb -> op0
  const size_t oD    = 26374144;                // 8 MB: sdb -> op1 | Ob
  const size_t oE    = 34762752;                // 32 MB
  const size_t total = oE + 33554432;           // 68,317,184
  if (ws_size < total) return;

  uint16_t* WT    = (uint16_t*)(ws + oWT);
  float*    biasc = (float*)(ws + oBias);
  float*    zp    = (float*)(ws + oZP);
  uint16_t* xb    = (uint16_t*)(ws + oC);
  uint16_t* op0   = (uint16_t*)(ws + oC);          // aliases xb (dead post-proj)
  uint16_t* sdb   = (uint16_t*)(ws + oD);
  uint16_t* Ob    = (uint16_t*)(ws + oD + 4194304);
  char* E = ws + oE;
  uint16_t* qkv  = (uint16_t*)(E);                  // 12 MB
  uint16_t* sqk0 = (uint16_t*)(E + 12582912);       // 8 MB
  uint16_t* sqk1 = (uint16_t*)(E + 20971520);       // 8 MB
  uint16_t* vTp  = (uint16_t*)(E + 29360128);       // 4 MB
  // post-attention aliases (qkv/sqk/vT dead after attn_o):
  float*    x1   = (float*)(E);                     // 8 MB
  float*    x1n  = (float*)(E + 8388608);           // 8 MB
  uint16_t* x1nb = (uint16_t*)(E + 16777216);       // 4 MB
  uint16_t* hb   = (uint16_t*)(E + 20971520);       // 4 MB
  float*    x2   = (float*)(E + 25165824);          // 8 MB

  wtrans_all<<<dim3(32, 32, 17), dim3(32, 8), 0, stream>>>(
      Wq, Wk, Wv, sWq, sWk, sWq + 1048576, sWk + 1048576, Wo, W1, W2, WT,
      bq, bk, bv, sbq, sbk, biasc, id_x, side, xb, sdb);

  proj_k<<<896, 256, 0, stream>>>(xb, sdb, WT, biasc, qkv, sqk0, sqk1, vTp);

  attn_z<<<1024, 256, 0, stream>>>(qkv, sqk0, sqk1, zp);
  attn_o<<<1024, 256, 0, stream>>>(qkv, sqk0, sqk1, vTp, zp, op0);
  ored_k<<<2048, 256, 0, stream>>>(op0, op0 + 2097152, Ob);

  gemm64_k<EPI_RES><<<dim3(16, 32), 256, 0, stream>>>(Ob, 1024, WT + 7340032, bo, id_x, x1, 1024);
  ln_k<1><<<2048, 256, 0, stream>>>(x1, g1, be1, x1n, x1nb);
  gemm64_k<EPI_GELU><<<dim3(16, 32), 256, 0, stream>>>(x1nb, 1024, WT + 8388608, b1, nullptr, hb, 1024);
  gemm64_k<EPI_RES><<<dim3(16, 32), 256, 0, stream>>>(hb, 1024, WT + 9437184, b2, x1n, x2, 1024);
  ln_k<0><<<2048, 256, 0, stream>>>(x2, g2, be2, (float*)d_out, nullptr);
}

// Round 13
// 181.196 us; speedup vs baseline: 1.1618x; 1.0130x over previous
//
#include <hip/hip_runtime.h>
#include <hip/hip_bf16.h>
#include <stdint.h>

typedef float   f32x4  __attribute__((ext_vector_type(4)));
typedef __bf16  bf16x8 __attribute__((ext_vector_type(8)));
typedef unsigned short u16x4 __attribute__((ext_vector_type(4)));
typedef unsigned short u16x8 __attribute__((ext_vector_type(8)));

__device__ __forceinline__ uint16_t f2b(float x) {
  union { float f; uint32_t u; } c; c.f = x;
  uint32_t u = c.u;
  return (uint16_t)((u + 0x7FFFu + ((u >> 16) & 1u)) >> 16);
}
__device__ __forceinline__ float b2f(uint16_t x) {
  union { uint32_t u; float f; } c; c.u = ((uint32_t)x) << 16;
  return c.f;
}

__device__ __forceinline__ f32x4 mfma32(bf16x8 a, bf16x8 b, f32x4 c) {
  return __builtin_amdgcn_mfma_f32_16x16x32_bf16(a, b, c, 0, 0, 0);
}

#define GLDS16(g, l) __builtin_amdgcn_global_load_lds( \
    (const __attribute__((address_space(1))) void*)(const void*)(g), \
    (__attribute__((address_space(3))) void*)(void*)(l), 16, 0, 0)

#define WAITVM(N) asm volatile("s_waitcnt vmcnt(" #N ")" ::: "memory")
#define WAITLGKM0 asm volatile("s_waitcnt lgkmcnt(0)" ::: "memory")
#define BAR() __builtin_amdgcn_s_barrier()

// -------- weight transposes + bias concat (z=10) + fp32->bf16 (z=11..16) ----
__global__ __launch_bounds__(256) void wtrans_all(
    const float* __restrict__ W0, const float* __restrict__ W1,
    const float* __restrict__ W2, const float* __restrict__ W3,
    const float* __restrict__ W4, const float* __restrict__ W5,
    const float* __restrict__ W6, const float* __restrict__ W7,
    const float* __restrict__ W8, const float* __restrict__ W9,
    uint16_t* __restrict__ WT,
    const float* __restrict__ bq, const float* __restrict__ bk,
    const float* __restrict__ bv, const float* __restrict__ sbq,
    const float* __restrict__ sbk, float* __restrict__ biasc,
    const float* __restrict__ id_x, const float* __restrict__ side,
    uint16_t* __restrict__ xb, uint16_t* __restrict__ sdb) {
  __shared__ float tl[32][33];
  const int tx = threadIdx.x, ty = threadIdx.y; // (32, 8)
  if (blockIdx.z >= 11) {
    size_t zi = blockIdx.z - 11;
    size_t base = ((zi * 1024 + blockIdx.y * 32 + blockIdx.x) * 256
                   + ty * 32 + tx) * 4;
    const float* in; uint16_t* out;
    if (base < 2097152) { in = id_x; out = xb; }
    else { in = side; out = sdb; base -= 2097152; }
    f32x4 v = *(const f32x4*)(in + base);
    u16x4 o;
    o[0] = f2b(v[0]); o[1] = f2b(v[1]); o[2] = f2b(v[2]); o[3] = f2b(v[3]);
    *(u16x4*)(out + base) = o;
    return;
  }
  if (blockIdx.z == 10) {
    int i = (blockIdx.y * 32 + blockIdx.x) * 256 + ty * 32 + tx;
    if (i < 7168) {
      int seg = i >> 10, off = i & 1023;
      float v;
      switch (seg) {
        case 0: v = bq[off]; break;
        case 1: v = bk[off]; break;
        case 2: v = bv[off]; break;
        case 3: v = sbq[off]; break;
        case 4: v = sbk[off]; break;
        case 5: v = sbq[1024 + off]; break;
        default: v = sbk[1024 + off]; break;
      }
      biasc[i] = v;
    }
    return;
  }
  const float* W;
  switch (blockIdx.z) {
    case 0: W = W0; break; case 1: W = W1; break; case 2: W = W2; break;
    case 3: W = W3; break; case 4: W = W4; break; case 5: W = W5; break;
    case 6: W = W6; break; case 7: W = W7; break; case 8: W = W8; break;
    default: W = W9; break;
  }
  uint16_t* dst = WT + (size_t)blockIdx.z * 1048576;
  const int n0 = blockIdx.x * 32, k0 = blockIdx.y * 32;
#pragma unroll
  for (int i = 0; i < 32; i += 8)
    tl[ty + i][tx] = W[(size_t)(k0 + ty + i) * 1024 + n0 + tx];
  __syncthreads();
#pragma unroll
  for (int i = 0; i < 32; i += 8)
    dst[(size_t)(n0 + ty + i) * 1024 + k0 + tx] = f2b(tl[tx][ty + i]);
}

// ---------------- merged projection GEMM (qkv + side0 + side1), 896 blocks ----
// 512 threads = 8 waves (4x2 wave grid, per-wave 32x64, acc[2][4]): doubles
// waves/SIMD (2->4) at the same 64 KB LDS / 2 blocks/CU. XOR-swizzled
// row-major LDS (0 conflicts), BK=64, 2 buffers, steady vmcnt(4).
__global__ __launch_bounds__(512) void proj_k(
    const uint16_t* __restrict__ xb, const uint16_t* __restrict__ sdb,
    const uint16_t* __restrict__ WT, const float* __restrict__ biasc,
    uint16_t* __restrict__ qkv, uint16_t* __restrict__ sqk0,
    uint16_t* __restrict__ sqk1, uint16_t* __restrict__ vT) {
  __shared__ uint16_t As[2][8192];
  __shared__ uint16_t Bs[2][8192];
  const int xcd = blockIdx.x & 7, s = blockIdx.x >> 3;  // s in [0,112)
  const uint16_t* A; const uint16_t* BT; const float* bias; uint16_t* C;
  int lda, ldc, bx, by;
  bool dovt = false;
  if (s < 48) {
    bx = xcd * 3 + s % 3; by = s / 3;
    A = xb; lda = 1024; BT = WT; bias = biasc; C = qkv; ldc = 3072;
    dovt = bx >= 16;
  } else if (s < 80) {
    int r = s - 48; bx = xcd * 2 + (r & 1); by = r >> 1;
    A = sdb; lda = 2048; BT = WT + 3145728; bias = biasc + 3072;
    C = sqk0; ldc = 2048;
  } else {
    int r = s - 80; bx = xcd * 2 + (r & 1); by = r >> 1;
    A = sdb + 1024; lda = 2048; BT = WT + 5242880; bias = biasc + 5120;
    C = sqk1; ldc = 2048;
  }
  const int t = threadIdx.x;
  const int lane = t & 63, w = t >> 6;       // 8 waves
  const int wr = w >> 1, wc = w & 1;         // 4 x 2 wave grid
  const int l15 = lane & 15, g = lane >> 4;
  const int bm0 = by * 128, bn0 = bx * 128;

  // staging: thread t covers row t>>2 (0..127), swizzled granule
  const int scol = ((t & 3) ^ ((t >> 3) & 3)) * 8;
  const uint16_t* ga = A  + (size_t)(bm0 + (t >> 2)) * lda  + scol;
  const uint16_t* gb = BT + (size_t)(bn0 + (t >> 2)) * 1024 + scol;
  const int gsw = (g ^ ((l15 >> 1) & 3)) * 8;

#define GSTAGE(bufi, k0) do { \
    GLDS16(ga + (k0),      &As[bufi][t * 8]); \
    GLDS16(ga + (k0) + 32, &As[bufi][4096 + t * 8]); \
    GLDS16(gb + (k0),      &Bs[bufi][t * 8]); \
    GLDS16(gb + (k0) + 32, &Bs[bufi][4096 + t * 8]); } while (0)

  f32x4 acc[2][4] = {};
  GSTAGE(0, 0);
  int cur = 0;
  for (int it = 0; it < 16; it++) {
    if (it < 15) { GSTAGE(cur ^ 1, (it + 1) * 64); WAITVM(4); }
    else WAITVM(0);
    BAR();
#pragma unroll
    for (int hf = 0; hf < 2; hf++) {
      const int ho = hf * 4096;
      bf16x8 af[2], bf[4];
#pragma unroll
      for (int i = 0; i < 2; i++)
        af[i] = *(const bf16x8*)&As[cur][ho + (wr * 32 + i * 16 + l15) * 32 + gsw];
#pragma unroll
      for (int i = 0; i < 4; i++)
        bf[i] = *(const bf16x8*)&Bs[cur][ho + (wc * 64 + i * 16 + l15) * 32 + gsw];
#pragma unroll
      for (int mi = 0; mi < 2; mi++)
#pragma unroll
        for (int ni = 0; ni < 4; ni++)
          acc[mi][ni] = mfma32(af[mi], bf[ni], acc[mi][ni]);
    }
    WAITLGKM0;
    BAR();
    cur ^= 1;
  }
#undef GSTAGE

#pragma unroll
  for (int mi = 0; mi < 2; mi++) {
#pragma unroll
    for (int ni = 0; ni < 4; ni++) {
      const int row0 = bm0 + wr * 32 + mi * 16 + g * 4;
      const int col  = bn0 + wc * 64 + ni * 16 + l15;
      const float bc = bias[col];
      u16x4 ov;
#pragma unroll
      for (int r = 0; r < 4; r++) {
        float v = acc[mi][ni][r] + bc;
        ov[r] = f2b(v);
        C[(size_t)(row0 + r) * ldc + col] = ov[r];
      }
      if (dovt) {
        const int cc = col - 2048, hh = cc >> 6, dd = cc & 63;
        const int bb = row0 >> 10, s0 = row0 & 1023;
        *(u16x4*)&vT[((size_t)((bb * 16 + hh) * 64 + dd)) * 1024 + s0] = ov;
      }
    }
  }
}

// ---------------- GEMM 64x64 (512 blocks; BK=64; 4-buffer single-barrier) ----
enum { EPI_BF16 = 0, EPI_RES = 1, EPI_GELU = 2 };

template<int EPI>
__global__ __launch_bounds__(256) void gemm64_k(
    const uint16_t* __restrict__ A, int lda,
    const uint16_t* __restrict__ BT,
    const float* __restrict__ bias,
    const float* __restrict__ res,
    void* __restrict__ Cv, int ldc) {
  __shared__ uint16_t As[4][4096];
  __shared__ uint16_t Bs[4][4096];
  const int t = threadIdx.x;
  const int lane = t & 63, w = t >> 6;
  const int wr = w >> 1, wc = w & 1;
  const int l15 = lane & 15, g = lane >> 4;
  const int bm0 = blockIdx.y * 64, bn0 = blockIdx.x * 64;

  const int scol = ((t & 3) ^ ((t >> 3) & 3)) * 8;
  const uint16_t* ga = A  + (size_t)(bm0 + (t >> 2)) * lda  + scol;
  const uint16_t* gb = BT + (size_t)(bn0 + (t >> 2)) * 1024 + scol;
  const int gsw = (g ^ ((l15 >> 1) & 3)) * 8;

#define GSTAGE64(bufi, k0) do { \
    GLDS16(ga + (k0),      &As[bufi][t * 8]); \
    GLDS16(ga + (k0) + 32, &As[bufi][2048 + t * 8]); \
    GLDS16(gb + (k0),      &Bs[bufi][t * 8]); \
    GLDS16(gb + (k0) + 32, &Bs[bufi][2048 + t * 8]); } while (0)

  f32x4 acc[2][2] = {};
  GSTAGE64(0, 0);
  GSTAGE64(1, 64);
  int cur = 0;
  for (int it = 0; it < 16; it++) {
    if (it < 14) {
      GSTAGE64((cur + 2) & 3, (it + 2) * 64);
      WAITVM(8);
    } else if (it == 14) {
      WAITVM(4);
    } else {
      WAITVM(0);
    }
    BAR();
#pragma unroll
    for (int hf = 0; hf < 2; hf++) {
      const int ho = hf * 2048;
      bf16x8 af[2], bf[2];
#pragma unroll
      for (int i = 0; i < 2; i++)
        af[i] = *(const bf16x8*)&As[cur][ho + (wr * 32 + i * 16 + l15) * 32 + gsw];
#pragma unroll
      for (int i = 0; i < 2; i++)
        bf[i] = *(const bf16x8*)&Bs[cur][ho + (wc * 32 + i * 16 + l15) * 32 + gsw];
#pragma unroll
      for (int mi = 0; mi < 2; mi++)
#pragma unroll
        for (int ni = 0; ni < 2; ni++)
          acc[mi][ni] = mfma32(af[mi], bf[ni], acc[mi][ni]);
    }
    cur = (cur + 1) & 3;
  }
#undef GSTAGE64

#pragma unroll
  for (int mi = 0; mi < 2; mi++) {
#pragma unroll
    for (int ni = 0; ni < 2; ni++) {
      const int row0 = bm0 + wr * 32 + mi * 16 + g * 4;
      const int col  = bn0 + wc * 32 + ni * 16 + l15;
      const float bc = bias[col];
#pragma unroll
      for (int r = 0; r < 4; r++) {
        float v = acc[mi][ni][r] + bc;
        const size_t idx = (size_t)(row0 + r) * ldc + col;
        if constexpr (EPI == EPI_RES) {
          ((float*)Cv)[idx] = v + res[idx];
        } else if constexpr (EPI == EPI_GELU) {
          float gl = 0.5f * v * (1.0f + erff(v * 0.70710678118654752f));
          ((uint16_t*)Cv)[idx] = f2b(gl);
        } else {
          ((uint16_t*)Cv)[idx] = f2b(v);
        }
      }
    }
  }
}

// ---------------- attention pass 1: Z partials (k-split, 3-buffer 2-deep) ----
__global__ __launch_bounds__(256) void attn_z(
    const uint16_t* __restrict__ qkv,
    const uint16_t* __restrict__ sqk0,
    const uint16_t* __restrict__ sqk1,
    float* __restrict__ zp) {
  __shared__ uint16_t Ks0[3][2048];
  __shared__ uint16_t Ks1[3][2048];
  __shared__ uint16_t Ks2[3][2048];
  const int t = threadIdx.x;
  const int lane = t & 63, w = t >> 6;
  const int l15 = lane & 15, g = lane >> 4;
  const int bid = blockIdx.x;
  const int xcd = bid & 7, idx = bid >> 3;
  const int grp = xcd * 8 + (idx >> 4);
  const int qt = idx & 15;
  const int hb = grp >> 1, kc = grp & 1;
  const int b = hb >> 4, h = hb & 15;
  const int q0 = qt * 64 + w * 16;
  const float scl2 = 0.03125f * 1.44269504088896f;
  const size_t rq = (size_t)(b * 1024 + q0 + l15);

  bf16x8 qf[3][2];
  {
    const uint16_t* p = qkv + rq * 3072 + h * 64 + g * 8;
    qf[0][0] = *(const bf16x8*)p; qf[0][1] = *(const bf16x8*)(p + 32);
    p = sqk0 + rq * 2048 + h * 64 + g * 8;
    qf[1][0] = *(const bf16x8*)p; qf[1][1] = *(const bf16x8*)(p + 32);
    p = sqk1 + rq * 2048 + h * 64 + g * 8;
    qf[2][0] = *(const bf16x8*)p; qf[2][1] = *(const bf16x8*)(p + 32);
  }

  const int p_   = t & 15;
  const int gg_  = (t >> 4) & 3;
  const int hf_  = (t >> 6) & 1;
  const int stq_ = t >> 7;
  const int srow   = (p_ >> 2) * 8 + stq_ * 4 + (p_ & 3) + kc * 512;
  const int kcolel = hf_ * 32 + gg_ * 8;

  const uint16_t* pk0 = qkv  + (size_t)b * 1024 * 3072 + 1024 + h * 64
                      + (size_t)srow * 3072 + kcolel;
  const uint16_t* pk1 = sqk0 + (size_t)b * 1024 * 2048 + 1024 + h * 64
                      + (size_t)srow * 2048 + kcolel;
  const uint16_t* pk2 = sqk1 + (size_t)b * 1024 * 2048 + 1024 + h * 64
                      + (size_t)srow * 2048 + kcolel;

#define STAGE3(bufi) do { \
    GLDS16(pk0, &Ks0[bufi][t * 8]); \
    GLDS16(pk1, &Ks1[bufi][t * 8]); \
    GLDS16(pk2, &Ks2[bufi][t * 8]); \
    pk0 += 32 * 3072; pk1 += 32 * 2048; pk2 += 32 * 2048; } while (0)

  float z0 = 0.f, z1 = 0.f, z2 = 0.f;
  STAGE3(0);
  STAGE3(1);
  int cur = 0;
  for (int kt = 0; kt < 16; kt++) {
    if (kt < 14) {
      int pre = cur + 2; if (pre >= 3) pre -= 3;
      STAGE3(pre);
      WAITVM(6);
    } else if (kt == 14) {
      WAITVM(3);
    } else {
      WAITVM(0);
    }
    BAR();
#pragma unroll
    for (int st = 0; st < 2; st++) {
      f32x4 c0 = {}, c1 = {}, c2 = {};
      c0 = mfma32(*(const bf16x8*)&Ks0[cur][st * 1024 + lane * 8],       qf[0][0], c0);
      c0 = mfma32(*(const bf16x8*)&Ks0[cur][st * 1024 + 512 + lane * 8], qf[0][1], c0);
      c1 = mfma32(*(const bf16x8*)&Ks1[cur][st * 1024 + lane * 8],       qf[1][0], c1);
      c1 = mfma32(*(const bf16x8*)&Ks1[cur][st * 1024 + 512 + lane * 8], qf[1][1], c1);
      c2 = mfma32(*(const bf16x8*)&Ks2[cur][st * 1024 + lane * 8],       qf[2][0], c2);
      c2 = mfma32(*(const bf16x8*)&Ks2[cur][st * 1024 + 512 + lane * 8], qf[2][1], c2);
#pragma unroll
      for (int r = 0; r < 4; r++) {
        z0 += __builtin_amdgcn_exp2f(c0[r] * scl2);
        z1 += __builtin_amdgcn_exp2f(c1[r] * scl2);
        z2 += __builtin_amdgcn_exp2f(c2[r] * scl2);
      }
    }
    WAITLGKM0;
    BAR();
    cur = (cur + 1 == 3) ? 0 : cur + 1;
  }
#undef STAGE3
  z0 += __shfl_xor(z0, 16, 64); z0 += __shfl_xor(z0, 32, 64);
  z1 += __shfl_xor(z1, 16, 64); z1 += __shfl_xor(z1, 32, 64);
  z2 += __shfl_xor(z2, 16, 64); z2 += __shfl_xor(z2, 32, 64);
  if (lane < 16) {
    const int qi = hb * 1024 + q0 + l15;
    zp[kc * 32768 + qi]          = z0;
    zp[65536 + kc * 32768 + qi]  = z1;
    zp[131072 + kc * 32768 + qi] = z2;
  }
}

// ---------------- attention pass 2 (zred inlined): partial O ----------------
__global__ __launch_bounds__(256) void attn_o(
    const uint16_t* __restrict__ qkv,
    const uint16_t* __restrict__ sqk0,
    const uint16_t* __restrict__ sqk1,
    const uint16_t* __restrict__ vT,
    const float* __restrict__ zp,
    uint16_t* __restrict__ op) {
  __shared__ uint16_t Ks0[2][2048];
  __shared__ uint16_t Ks1[2][2048];
  __shared__ uint16_t Ks2[2][2048];
  __shared__ uint16_t Vs[2][2048];
  const int t = threadIdx.x;
  const int lane = t & 63, w = t >> 6;
  const int l15 = lane & 15, g = lane >> 4;
  const int bid = blockIdx.x;
  const int xcd = bid & 7, idx = bid >> 3;
  const int grp = xcd * 8 + (idx >> 4);
  const int qt = idx & 15;
  const int hb = grp >> 1, kc = grp & 1;
  const int b = hb >> 4, h = hb & 15;
  const int q0 = qt * 64 + w * 16;
  const float scl2 = 0.03125f * 1.44269504088896f;
  const size_t rq = (size_t)(b * 1024 + q0 + l15);

  bf16x8 qf[3][2];
  {
    const uint16_t* p = qkv + rq * 3072 + h * 64 + g * 8;
    qf[0][0] = *(const bf16x8*)p; qf[0][1] = *(const bf16x8*)(p + 32);
    p = sqk0 + rq * 2048 + h * 64 + g * 8;
    qf[1][0] = *(const bf16x8*)p; qf[1][1] = *(const bf16x8*)(p + 32);
    p = sqk1 + rq * 2048 + h * 64 + g * 8;
    qf[2][0] = *(const bf16x8*)p; qf[2][1] = *(const bf16x8*)(p + 32);
  }
  const int qi = hb * 1024 + q0 + l15;
  const float lz0 = __builtin_amdgcn_logf(zp[qi] + zp[qi + 32768]);
  const float lz1 = __builtin_amdgcn_logf(zp[qi + 65536] + zp[qi + 98304]);
  const float lz2 = __builtin_amdgcn_logf(zp[qi + 131072] + zp[qi + 163840]);

  const int p_   = t & 15;
  const int gg_  = (t >> 4) & 3;
  const int hf_  = (t >> 6) & 1;
  const int stq_ = t >> 7;
  const int srow   = (p_ >> 2) * 8 + stq_ * 4 + (p_ & 3) + kc * 512;
  const int kcolel = hf_ * 32 + gg_ * 8;

  const uint16_t* pk0 = qkv  + (size_t)b * 1024 * 3072 + 1024 + h * 64
                      + (size_t)srow * 3072 + kcolel;
  const uint16_t* pk1 = sqk0 + (size_t)b * 1024 * 2048 + 1024 + h * 64
                      + (size_t)srow * 2048 + kcolel;
  const uint16_t* pk2 = sqk1 + (size_t)b * 1024 * 2048 + 1024 + h * 64
                      + (size_t)srow * 2048 + kcolel;
  const uint16_t* pv  = vT + ((size_t)hb * 64 + (t >> 6) * 16 + p_) * 1024
                      + kc * 512 + gg_ * 8;

#define STAGE4(bufi) do { \
    GLDS16(pk0, &Ks0[bufi][t * 8]); \
    GLDS16(pk1, &Ks1[bufi][t * 8]); \
    GLDS16(pk2, &Ks2[bufi][t * 8]); \
    GLDS16(pv,  &Vs[bufi][t * 8]); \
    pk0 += 32 * 3072; pk1 += 32 * 2048; pk2 += 32 * 2048; pv += 32; } while (0)

  f32x4 accO[4] = {};
  int cur = 0;
  STAGE4(0);
  for (int kt = 0; kt < 16; kt++) {
    if (kt < 15) { STAGE4(cur ^ 1); WAITVM(4); }
    else WAITVM(0);
    BAR();
    u16x8 pu;
#pragma unroll
    for (int sub = 0; sub < 2; sub++) {
      f32x4 c0 = {}, c1 = {}, c2 = {};
      c0 = mfma32(*(const bf16x8*)&Ks0[cur][sub * 1024 + lane * 8],       qf[0][0], c0);
      c0 = mfma32(*(const bf16x8*)&Ks0[cur][sub * 1024 + 512 + lane * 8], qf[0][1], c0);
      c1 = mfma32(*(const bf16x8*)&Ks1[cur][sub * 1024 + lane * 8],       qf[1][0], c1);
      c1 = mfma32(*(const bf16x8*)&Ks1[cur][sub * 1024 + 512 + lane * 8], qf[1][1], c1);
      c2 = mfma32(*(const bf16x8*)&Ks2[cur][sub * 1024 + lane * 8],       qf[2][0], c2);
      c2 = mfma32(*(const bf16x8*)&Ks2[cur][sub * 1024 + 512 + lane * 8], qf[2][1], c2);
#pragma unroll
      for (int r = 0; r < 4; r++) {
        float m = fmaxf(fmaxf(c0[r] * scl2 - lz0, c1[r] * scl2 - lz1),
                        c2[r] * scl2 - lz2);
        pu[sub * 4 + r] = f2b(__builtin_amdgcn_exp2f(m));
      }
    }
    const bf16x8 pf = __builtin_bit_cast(bf16x8, pu);
#pragma unroll
    for (int dt = 0; dt < 4; dt++) {
      bf16x8 vf = *(const bf16x8*)&Vs[cur][dt * 512 + lane * 8];
      accO[dt] = mfma32(vf, pf, accO[dt]);
    }
    WAITLGKM0;
    BAR();
    cur ^= 1;
  }
#undef STAGE4

  uint16_t* ob = op + (size_t)kc * 2097152 + rq * 1024 + h * 64;
#pragma unroll
  for (int dt = 0; dt < 4; dt++) {
    u16x4 o4;
#pragma unroll
    for (int r = 0; r < 4; r++) o4[r] = f2b(accO[dt][r]);
    *(u16x4*)(ob + dt * 16 + g * 4) = o4;
  }
}

// ---------------- O partial reduce: Ob = bf16(op0 + op1) ----------------
__global__ __launch_bounds__(256) void ored_k(const uint16_t* __restrict__ op0,
                                              const uint16_t* __restrict__ op1,
                                              uint16_t* __restrict__ Ob) {
  int i = (blockIdx.x * 256 + threadIdx.x) * 4;
  u16x4 a = *(const u16x4*)(op0 + i);
  u16x4 b = *(const u16x4*)(op1 + i);
  u16x4 o;
#pragma unroll
  for (int j = 0; j < 4; j++) o[j] = f2b(b2f(a[j]) + b2f(b[j]));
  *(u16x4*)(Ob + i) = o;
}

// ---------------- LayerNorm over rows of 1024 fp32, optional bf16 copy ----------------
template<int WB>
__global__ __launch_bounds__(256) void ln_k(const float* __restrict__ X,
                                            const float* __restrict__ G,
                                            const float* __restrict__ Bt,
                                            float* __restrict__ Yf,
                                            uint16_t* __restrict__ Yb) {
  const int row = blockIdx.x, t = threadIdx.x;
  const int lane = t & 63, w = t >> 6;
  const size_t base = (size_t)row * 1024 + t * 4;
  f32x4 x = *(const f32x4*)(X + base);
  float s  = x[0] + x[1] + x[2] + x[3];
  float s2 = x[0] * x[0] + x[1] * x[1] + x[2] * x[2] + x[3] * x[3];
#pragma unroll
  for (int o = 1; o < 64; o <<= 1) {
    s  += __shfl_xor(s,  o, 64);
    s2 += __shfl_xor(s2, o, 64);
  }
  __shared__ float red[8];
  if (lane == 0) { red[w] = s; red[4 + w] = s2; }
  __syncthreads();
  s  = red[0] + red[1] + red[2] + red[3];
  s2 = red[4] + red[5] + red[6] + red[7];
  const float mean = s * (1.0f / 1024.0f);
  const float rstd = rsqrtf(s2 * (1.0f / 1024.0f) - mean * mean + 1e-5f);
  f32x4 gv = *(const f32x4*)(G + t * 4);
  f32x4 bv = *(const f32x4*)(Bt + t * 4);
  f32x4 y;
#pragma unroll
  for (int i = 0; i < 4; i++) y[i] = (x[i] - mean) * rstd * gv[i] + bv[i];
  *(f32x4*)(Yf + base) = y;
  if constexpr (WB) {
    u16x4 o;
#pragma unroll
    for (int i = 0; i < 4; i++) o[i] = f2b(y[i]);
    *(u16x4*)(Yb + base) = o;
  }
}

// ---------------- host ----------------
extern "C" void kernel_launch(void* const* d_in, const int* in_sizes, int n_in,
                              void* d_out, int out_size, void* d_ws, size_t ws_size,
                              hipStream_t stream) {
  (void)in_sizes; (void)n_in; (void)out_size;
  const float* id_x = (const float*)d_in[0];
  const float* side = (const float*)d_in[1];
  const float* Wq  = (const float*)d_in[3];
  const float* bq  = (const float*)d_in[4];
  const float* Wk  = (const float*)d_in[5];
  const float* bk  = (const float*)d_in[6];
  const float* Wv  = (const float*)d_in[7];
  const float* bv  = (const float*)d_in[8];
  const float* sWq = (const float*)d_in[9];
  const float* sbq = (const float*)d_in[10];
  const float* sWk = (const float*)d_in[11];
  const float* sbk = (const float*)d_in[12];
  const float* Wo  = (const float*)d_in[13];
  const float* bo  = (const float*)d_in[14];
  const float* W1  = (const float*)d_in[15];
  const float* b1  = (const float*)d_in[16];
  const float* W2  = (const float*)d_in[17];
  const float* b2  = (const float*)d_in[18];
  const float* g1  = (const float*)d_in[19];
  const float* be1 = (const float*)d_in[20];
  const float* g2  = (const float*)d_in[21];
  const float* be2 = (const float*)d_in[22];

  char* ws = (char*)d_ws;
  const size_t oWT   = 0;                       // 10x 1024x1024 bf16 = 20,971,520
  const size_t oBias = 20971520;                // 7168 f32 = 28,672
  const size_t oZP   = 21000192;                // 3*65536 f32 = 786,432
  const size_t oC    = 22179840;                // 4 MB: xb -> op0
  const size_t oD    = 26374144;                // 8 MB: sdb -> op1 | Ob
  const size_t oE    = 34762752;                // 32 MB
  const size_t total = oE + 33554432;           // 68,317,184
  if (ws_size < total) return;

  uint16_t* WT    = (uint16_t*)(ws + oWT);
  float*    biasc = (float*)(ws + oBias);
  float*    zp    = (float*)(ws + oZP);
  uint16_t* xb    = (uint16_t*)(ws + oC);
  uint16_t* op0   = (uint16_t*)(ws + oC);          // aliases xb (dead post-proj)
  uint16_t* sdb   = (uint16_t*)(ws + oD);
  uint16_t* Ob    = (uint16_t*)(ws + oD + 4194304);
  char* E = ws + oE;
  uint16_t* qkv  = (uint16_t*)(E);                  // 12 MB
  uint16_t* sqk0 = (uint16_t*)(E + 12582912);       // 8 MB
  uint16_t* sqk1 = (uint16_t*)(E + 20971520);       // 8 MB
  uint16_t* vTp  = (uint16_t*)(E + 29360128);       // 4 MB
  // post-attention aliases (qkv/sqk/vT dead after attn_o):
  float*    x1   = (float*)(E);                     // 8 MB
  float*    x1n  = (float*)(E + 8388608);           // 8 MB
  uint16_t* x1nb = (uint16_t*)(E + 16777216);       // 4 MB
  uint16_t* hb   = (uint16_t*)(E + 20971520);       // 4 MB
  float*    x2   = (float*)(E + 25165824);          // 8 MB

  wtrans_all<<<dim3(32, 32, 17), dim3(32, 8), 0, stream>>>(
      Wq, Wk, Wv, sWq, sWk, sWq + 1048576, sWk + 1048576, Wo, W1, W2, WT,
      bq, bk, bv, sbq, sbk, biasc, id_x, side, xb, sdb);

  proj_k<<<896, 512, 0, stream>>>(xb, sdb, WT, biasc, qkv, sqk0, sqk1, vTp);

  attn_z<<<1024, 256, 0, stream>>>(qkv, sqk0, sqk1, zp);
  attn_o<<<1024, 256, 0, stream>>>(qkv, sqk0, sqk1, vTp, zp, op0);
  ored_k<<<2048, 256, 0, stream>>>(op0, op0 + 2097152, Ob);

  gemm64_k<EPI_RES><<<dim3(16, 32), 256, 0, stream>>>(Ob, 1024, WT + 7340032, bo, id_x, x1, 1024);
  ln_k<1><<<2048, 256, 0, stream>>>(x1, g1, be1, x1n, x1nb);
  gemm64_k<EPI_GELU><<<dim3(16, 32), 256, 0, stream>>>(x1nb, 1024, WT + 8388608, b1, nullptr, hb, 1024);
  gemm64_k<EPI_RES><<<dim3(16, 32), 256, 0, stream>>>(hb, 1024, WT + 9437184, b2, x1n, x2, 1024);
  ln_k<0><<<2048, 256, 0, stream>>>(x2, g2, be2, (float*)d_out, nullptr);
}

// Round 14
// 159.677 us; speedup vs baseline: 1.3184x; 1.1348x over previous
//
#include <hip/hip_runtime.h>
#include <hip/hip_bf16.h>
#include <stdint.h>

typedef float   f32x4  __attribute__((ext_vector_type(4)));
typedef __bf16  bf16x8 __attribute__((ext_vector_type(8)));
typedef unsigned short u16x4 __attribute__((ext_vector_type(4)));
typedef unsigned short u16x8 __attribute__((ext_vector_type(8)));

__device__ __forceinline__ uint16_t f2b(float x) {
  union { float f; uint32_t u; } c; c.f = x;
  uint32_t u = c.u;
  return (uint16_t)((u + 0x7FFFu + ((u >> 16) & 1u)) >> 16);
}
__device__ __forceinline__ float b2f(uint16_t x) {
  union { uint32_t u; float f; } c; c.u = ((uint32_t)x) << 16;
  return c.f;
}

__device__ __forceinline__ f32x4 mfma32(bf16x8 a, bf16x8 b, f32x4 c) {
  return __builtin_amdgcn_mfma_f32_16x16x32_bf16(a, b, c, 0, 0, 0);
}

#define GLDS16(g, l) __builtin_amdgcn_global_load_lds( \
    (const __attribute__((address_space(1))) void*)(const void*)(g), \
    (__attribute__((address_space(3))) void*)(void*)(l), 16, 0, 0)

#define WAITVM(N) asm volatile("s_waitcnt vmcnt(" #N ")" ::: "memory")
#define WAITLGKM0 asm volatile("s_waitcnt lgkmcnt(0)" ::: "memory")
#define BAR() __builtin_amdgcn_s_barrier()

// -------- weight transposes + bias concat (z=10) + fp32->bf16 (z=11..16) ----
__global__ __launch_bounds__(256) void wtrans_all(
    const float* __restrict__ W0, const float* __restrict__ W1,
    const float* __restrict__ W2, const float* __restrict__ W3,
    const float* __restrict__ W4, const float* __restrict__ W5,
    const float* __restrict__ W6, const float* __restrict__ W7,
    const float* __restrict__ W8, const float* __restrict__ W9,
    uint16_t* __restrict__ WT,
    const float* __restrict__ bq, const float* __restrict__ bk,
    const float* __restrict__ bv, const float* __restrict__ sbq,
    const float* __restrict__ sbk, float* __restrict__ biasc,
    const float* __restrict__ id_x, const float* __restrict__ side,
    uint16_t* __restrict__ xb, uint16_t* __restrict__ sdb) {
  __shared__ float tl[32][33];
  const int tx = threadIdx.x, ty = threadIdx.y; // (32, 8)
  if (blockIdx.z >= 11) {
    size_t zi = blockIdx.z - 11;
    size_t base = ((zi * 1024 + blockIdx.y * 32 + blockIdx.x) * 256
                   + ty * 32 + tx) * 4;
    const float* in; uint16_t* out;
    if (base < 2097152) { in = id_x; out = xb; }
    else { in = side; out = sdb; base -= 2097152; }
    f32x4 v = *(const f32x4*)(in + base);
    u16x4 o;
    o[0] = f2b(v[0]); o[1] = f2b(v[1]); o[2] = f2b(v[2]); o[3] = f2b(v[3]);
    *(u16x4*)(out + base) = o;
    return;
  }
  if (blockIdx.z == 10) {
    int i = (blockIdx.y * 32 + blockIdx.x) * 256 + ty * 32 + tx;
    if (i < 7168) {
      int seg = i >> 10, off = i & 1023;
      float v;
      switch (seg) {
        case 0: v = bq[off]; break;
        case 1: v = bk[off]; break;
        case 2: v = bv[off]; break;
        case 3: v = sbq[off]; break;
        case 4: v = sbk[off]; break;
        case 5: v = sbq[1024 + off]; break;
        default: v = sbk[1024 + off]; break;
      }
      biasc[i] = v;
    }
    return;
  }
  const float* W;
  switch (blockIdx.z) {
    case 0: W = W0; break; case 1: W = W1; break; case 2: W = W2; break;
    case 3: W = W3; break; case 4: W = W4; break; case 5: W = W5; break;
    case 6: W = W6; break; case 7: W = W7; break; case 8: W = W8; break;
    default: W = W9; break;
  }
  uint16_t* dst = WT + (size_t)blockIdx.z * 1048576;
  const int n0 = blockIdx.x * 32, k0 = blockIdx.y * 32;
#pragma unroll
  for (int i = 0; i < 32; i += 8)
    tl[ty + i][tx] = W[(size_t)(k0 + ty + i) * 1024 + n0 + tx];
  __syncthreads();
#pragma unroll
  for (int i = 0; i < 32; i += 8)
    dst[(size_t)(n0 + ty + i) * 1024 + k0 + tx] = f2b(tl[tx][ty + i]);
}

// ---------------- merged projection GEMM (512 threads, 896 blocks) ----------
__global__ __launch_bounds__(512) void proj_k(
    const uint16_t* __restrict__ xb, const uint16_t* __restrict__ sdb,
    const uint16_t* __restrict__ WT, const float* __restrict__ biasc,
    uint16_t* __restrict__ qkv, uint16_t* __restrict__ sqk0,
    uint16_t* __restrict__ sqk1, uint16_t* __restrict__ vT) {
  __shared__ uint16_t As[2][8192];
  __shared__ uint16_t Bs[2][8192];
  const int xcd = blockIdx.x & 7, s = blockIdx.x >> 3;  // s in [0,112)
  const uint16_t* A; const uint16_t* BT; const float* bias; uint16_t* C;
  int lda, ldc, bx, by;
  bool dovt = false;
  if (s < 48) {
    bx = xcd * 3 + s % 3; by = s / 3;
    A = xb; lda = 1024; BT = WT; bias = biasc; C = qkv; ldc = 3072;
    dovt = bx >= 16;
  } else if (s < 80) {
    int r = s - 48; bx = xcd * 2 + (r & 1); by = r >> 1;
    A = sdb; lda = 2048; BT = WT + 3145728; bias = biasc + 3072;
    C = sqk0; ldc = 2048;
  } else {
    int r = s - 80; bx = xcd * 2 + (r & 1); by = r >> 1;
    A = sdb + 1024; lda = 2048; BT = WT + 5242880; bias = biasc + 5120;
    C = sqk1; ldc = 2048;
  }
  const int t = threadIdx.x;
  const int lane = t & 63, w = t >> 6;       // 8 waves
  const int wr = w >> 1, wc = w & 1;         // 4 x 2 wave grid
  const int l15 = lane & 15, g = lane >> 4;
  const int bm0 = by * 128, bn0 = bx * 128;

  const int scol = ((t & 3) ^ ((t >> 3) & 3)) * 8;
  const uint16_t* ga = A  + (size_t)(bm0 + (t >> 2)) * lda  + scol;
  const uint16_t* gb = BT + (size_t)(bn0 + (t >> 2)) * 1024 + scol;
  const int gsw = (g ^ ((l15 >> 1) & 3)) * 8;

#define GSTAGE(bufi, k0) do { \
    GLDS16(ga + (k0),      &As[bufi][t * 8]); \
    GLDS16(ga + (k0) + 32, &As[bufi][4096 + t * 8]); \
    GLDS16(gb + (k0),      &Bs[bufi][t * 8]); \
    GLDS16(gb + (k0) + 32, &Bs[bufi][4096 + t * 8]); } while (0)

  f32x4 acc[2][4] = {};
  GSTAGE(0, 0);
  int cur = 0;
  for (int it = 0; it < 16; it++) {
    if (it < 15) { GSTAGE(cur ^ 1, (it + 1) * 64); WAITVM(4); }
    else WAITVM(0);
    BAR();
#pragma unroll
    for (int hf = 0; hf < 2; hf++) {
      const int ho = hf * 4096;
      bf16x8 af[2], bf[4];
#pragma unroll
      for (int i = 0; i < 2; i++)
        af[i] = *(const bf16x8*)&As[cur][ho + (wr * 32 + i * 16 + l15) * 32 + gsw];
#pragma unroll
      for (int i = 0; i < 4; i++)
        bf[i] = *(const bf16x8*)&Bs[cur][ho + (wc * 64 + i * 16 + l15) * 32 + gsw];
#pragma unroll
      for (int mi = 0; mi < 2; mi++)
#pragma unroll
        for (int ni = 0; ni < 4; ni++)
          acc[mi][ni] = mfma32(af[mi], bf[ni], acc[mi][ni]);
    }
    WAITLGKM0;
    BAR();
    cur ^= 1;
  }
#undef GSTAGE

#pragma unroll
  for (int mi = 0; mi < 2; mi++) {
#pragma unroll
    for (int ni = 0; ni < 4; ni++) {
      const int row0 = bm0 + wr * 32 + mi * 16 + g * 4;
      const int col  = bn0 + wc * 64 + ni * 16 + l15;
      const float bc = bias[col];
      u16x4 ov;
#pragma unroll
      for (int r = 0; r < 4; r++) {
        float v = acc[mi][ni][r] + bc;
        ov[r] = f2b(v);
        C[(size_t)(row0 + r) * ldc + col] = ov[r];
      }
      if (dovt) {
        const int cc = col - 2048, hh = cc >> 6, dd = cc & 63;
        const int bb = row0 >> 10, s0 = row0 & 1023;
        *(u16x4*)&vT[((size_t)((bb * 16 + hh) * 64 + dd)) * 1024 + s0] = ov;
      }
    }
  }
}

// ---------------- GEMM 64x64 (512 blocks; BK=64; 4-buffer single-barrier) ----
enum { EPI_BF16 = 0, EPI_RES = 1, EPI_GELU = 2 };

template<int EPI>
__global__ __launch_bounds__(256) void gemm64_k(
    const uint16_t* __restrict__ A, int lda,
    const uint16_t* __restrict__ BT,
    const float* __restrict__ bias,
    const float* __restrict__ res,
    void* __restrict__ Cv, int ldc) {
  __shared__ uint16_t As[4][4096];
  __shared__ uint16_t Bs[4][4096];
  const int t = threadIdx.x;
  const int lane = t & 63, w = t >> 6;
  const int wr = w >> 1, wc = w & 1;
  const int l15 = lane & 15, g = lane >> 4;
  const int bm0 = blockIdx.y * 64, bn0 = blockIdx.x * 64;

  const int scol = ((t & 3) ^ ((t >> 3) & 3)) * 8;
  const uint16_t* ga = A  + (size_t)(bm0 + (t >> 2)) * lda  + scol;
  const uint16_t* gb = BT + (size_t)(bn0 + (t >> 2)) * 1024 + scol;
  const int gsw = (g ^ ((l15 >> 1) & 3)) * 8;

#define GSTAGE64(bufi, k0) do { \
    GLDS16(ga + (k0),      &As[bufi][t * 8]); \
    GLDS16(ga + (k0) + 32, &As[bufi][2048 + t * 8]); \
    GLDS16(gb + (k0),      &Bs[bufi][t * 8]); \
    GLDS16(gb + (k0) + 32, &Bs[bufi][2048 + t * 8]); } while (0)

  f32x4 acc[2][2] = {};
  GSTAGE64(0, 0);
  GSTAGE64(1, 64);
  int cur = 0;
  for (int it = 0; it < 16; it++) {
    if (it < 14) {
      GSTAGE64((cur + 2) & 3, (it + 2) * 64);
      WAITVM(8);
    } else if (it == 14) {
      WAITVM(4);
    } else {
      WAITVM(0);
    }
    BAR();
#pragma unroll
    for (int hf = 0; hf < 2; hf++) {
      const int ho = hf * 2048;
      bf16x8 af[2], bf[2];
#pragma unroll
      for (int i = 0; i < 2; i++)
        af[i] = *(const bf16x8*)&As[cur][ho + (wr * 32 + i * 16 + l15) * 32 + gsw];
#pragma unroll
      for (int i = 0; i < 2; i++)
        bf[i] = *(const bf16x8*)&Bs[cur][ho + (wc * 32 + i * 16 + l15) * 32 + gsw];
#pragma unroll
      for (int mi = 0; mi < 2; mi++)
#pragma unroll
        for (int ni = 0; ni < 2; ni++)
          acc[mi][ni] = mfma32(af[mi], bf[ni], acc[mi][ni]);
    }
    cur = (cur + 1) & 3;
  }
#undef GSTAGE64

#pragma unroll
  for (int mi = 0; mi < 2; mi++) {
#pragma unroll
    for (int ni = 0; ni < 2; ni++) {
      const int row0 = bm0 + wr * 32 + mi * 16 + g * 4;
      const int col  = bn0 + wc * 32 + ni * 16 + l15;
      const float bc = bias[col];
#pragma unroll
      for (int r = 0; r < 4; r++) {
        float v = acc[mi][ni][r] + bc;
        const size_t idx = (size_t)(row0 + r) * ldc + col;
        if constexpr (EPI == EPI_RES) {
          ((float*)Cv)[idx] = v + res[idx];
        } else if constexpr (EPI == EPI_GELU) {
          float gl = 0.5f * v * (1.0f + erff(v * 0.70710678118654752f));
          ((uint16_t*)Cv)[idx] = f2b(gl);
        } else {
          ((uint16_t*)Cv)[idx] = f2b(v);
        }
      }
    }
  }
}

// ---------------- attention pass 1: Z partials (512 thr, shared K staging) ----
// 512 blocks: 8 waves share one K tile set; block covers 128 q rows.
// LDS regions per buffer: Ks0 @0, Ks1 @2048, Ks2 @4096 (elements).
// Staging: half 0 (waves 0-3) loads Ks0 + Ks2; half 1 (waves 4-7) loads Ks1.
__global__ __launch_bounds__(512) void attn_z(
    const uint16_t* __restrict__ qkv,
    const uint16_t* __restrict__ sqk0,
    const uint16_t* __restrict__ sqk1,
    float* __restrict__ zp) {
  __shared__ uint16_t Sh[2][6144];
  const int t = threadIdx.x;
  const int lane = t & 63, w = t >> 6;
  const int l15 = lane & 15, g = lane >> 4;
  const int half = t >> 8, th = t & 255;
  const int bid = blockIdx.x;
  const int xcd = bid & 7, idx = bid >> 3;
  const int grp = xcd * 8 + (idx >> 3);   // 0..63
  const int qt = idx & 7;
  const int hb = grp >> 1, kc = grp & 1;
  const int b = hb >> 4, h = hb & 15;
  const int q0 = qt * 128 + w * 16;
  const float scl2 = 0.03125f * 1.44269504088896f;
  const size_t rq = (size_t)(b * 1024 + q0 + l15);

  bf16x8 qf[3][2];
  {
    const uint16_t* p = qkv + rq * 3072 + h * 64 + g * 8;
    qf[0][0] = *(const bf16x8*)p; qf[0][1] = *(const bf16x8*)(p + 32);
    p = sqk0 + rq * 2048 + h * 64 + g * 8;
    qf[1][0] = *(const bf16x8*)p; qf[1][1] = *(const bf16x8*)(p + 32);
    p = sqk1 + rq * 2048 + h * 64 + g * 8;
    qf[2][0] = *(const bf16x8*)p; qf[2][1] = *(const bf16x8*)(p + 32);
  }

  const int p_   = th & 15;
  const int gg_  = (th >> 4) & 3;
  const int hf_  = (th >> 6) & 1;
  const int stq_ = th >> 7;
  const int srow   = (p_ >> 2) * 8 + stq_ * 4 + (p_ & 3) + kc * 512;
  const int kcolel = hf_ * 32 + gg_ * 8;

  const uint16_t* srcA = half
      ? sqk0 + (size_t)b * 1024 * 2048 + 1024 + h * 64 + (size_t)srow * 2048 + kcolel
      : qkv  + (size_t)b * 1024 * 3072 + 1024 + h * 64 + (size_t)srow * 3072 + kcolel;
  const size_t incA = half ? (size_t)32 * 2048 : (size_t)32 * 3072;
  const uint16_t* srcB = sqk1 + (size_t)b * 1024 * 2048 + 1024 + h * 64
                       + (size_t)srow * 2048 + kcolel;
  const int offA = half * 2048 + th * 8;
  const int offB = 4096 + th * 8;

#define STAGEZ(bufi) do { \
    GLDS16(srcA, &Sh[bufi][offA]); \
    if (!half) GLDS16(srcB, &Sh[bufi][offB]); \
    srcA += incA; srcB += 32 * 2048; } while (0)

  float z0 = 0.f, z1 = 0.f, z2 = 0.f;
  STAGEZ(0);
  int cur = 0;
  for (int kt = 0; kt < 16; kt++) {
    if (kt < 15) {
      STAGEZ(cur ^ 1);
      if (!half) WAITVM(2); else WAITVM(1);
    } else WAITVM(0);
    BAR();
#pragma unroll
    for (int st = 0; st < 2; st++) {
      f32x4 c0 = {}, c1 = {}, c2 = {};
      c0 = mfma32(*(const bf16x8*)&Sh[cur][st * 1024 + lane * 8],              qf[0][0], c0);
      c0 = mfma32(*(const bf16x8*)&Sh[cur][st * 1024 + 512 + lane * 8],        qf[0][1], c0);
      c1 = mfma32(*(const bf16x8*)&Sh[cur][2048 + st * 1024 + lane * 8],       qf[1][0], c1);
      c1 = mfma32(*(const bf16x8*)&Sh[cur][2048 + st * 1024 + 512 + lane * 8], qf[1][1], c1);
      c2 = mfma32(*(const bf16x8*)&Sh[cur][4096 + st * 1024 + lane * 8],       qf[2][0], c2);
      c2 = mfma32(*(const bf16x8*)&Sh[cur][4096 + st * 1024 + 512 + lane * 8], qf[2][1], c2);
#pragma unroll
      for (int r = 0; r < 4; r++) {
        z0 += __builtin_amdgcn_exp2f(c0[r] * scl2);
        z1 += __builtin_amdgcn_exp2f(c1[r] * scl2);
        z2 += __builtin_amdgcn_exp2f(c2[r] * scl2);
      }
    }
    WAITLGKM0;
    BAR();
    cur ^= 1;
  }
#undef STAGEZ
  z0 += __shfl_xor(z0, 16, 64); z0 += __shfl_xor(z0, 32, 64);
  z1 += __shfl_xor(z1, 16, 64); z1 += __shfl_xor(z1, 32, 64);
  z2 += __shfl_xor(z2, 16, 64); z2 += __shfl_xor(z2, 32, 64);
  if (lane < 16) {
    const int qi = hb * 1024 + q0 + l15;
    zp[kc * 32768 + qi]          = z0;
    zp[65536 + kc * 32768 + qi]  = z1;
    zp[131072 + kc * 32768 + qi] = z2;
  }
}

// ---------------- attention pass 2 (512 thr, shared K/V staging) ------------
// LDS regions per buffer: Ks0 @0, Ks1 @2048, Ks2 @4096, Vs @6144.
// Staging: half 0 loads Ks0 + Ks2; half 1 loads Ks1 + Vs.
__global__ __launch_bounds__(512) void attn_o(
    const uint16_t* __restrict__ qkv,
    const uint16_t* __restrict__ sqk0,
    const uint16_t* __restrict__ sqk1,
    const uint16_t* __restrict__ vT,
    const float* __restrict__ zp,
    uint16_t* __restrict__ op) {
  __shared__ uint16_t Sh[2][8192];
  const int t = threadIdx.x;
  const int lane = t & 63, w = t >> 6;
  const int l15 = lane & 15, g = lane >> 4;
  const int half = t >> 8, th = t & 255;
  const int bid = blockIdx.x;
  const int xcd = bid & 7, idx = bid >> 3;
  const int grp = xcd * 8 + (idx >> 3);
  const int qt = idx & 7;
  const int hb = grp >> 1, kc = grp & 1;
  const int b = hb >> 4, h = hb & 15;
  const int q0 = qt * 128 + w * 16;
  const float scl2 = 0.03125f * 1.44269504088896f;
  const size_t rq = (size_t)(b * 1024 + q0 + l15);

  bf16x8 qf[3][2];
  {
    const uint16_t* p = qkv + rq * 3072 + h * 64 + g * 8;
    qf[0][0] = *(const bf16x8*)p; qf[0][1] = *(const bf16x8*)(p + 32);
    p = sqk0 + rq * 2048 + h * 64 + g * 8;
    qf[1][0] = *(const bf16x8*)p; qf[1][1] = *(const bf16x8*)(p + 32);
    p = sqk1 + rq * 2048 + h * 64 + g * 8;
    qf[2][0] = *(const bf16x8*)p; qf[2][1] = *(const bf16x8*)(p + 32);
  }
  const int qi = hb * 1024 + q0 + l15;
  const float lz0 = __builtin_amdgcn_logf(zp[qi] + zp[qi + 32768]);
  const float lz1 = __builtin_amdgcn_logf(zp[qi + 65536] + zp[qi + 98304]);
  const float lz2 = __builtin_amdgcn_logf(zp[qi + 131072] + zp[qi + 163840]);

  const int p_   = th & 15;
  const int gg_  = (th >> 4) & 3;
  const int hf_  = (th >> 6) & 1;
  const int stq_ = th >> 7;
  const int srow   = (p_ >> 2) * 8 + stq_ * 4 + (p_ & 3) + kc * 512;
  const int kcolel = hf_ * 32 + gg_ * 8;

  const uint16_t* srcA = half
      ? sqk0 + (size_t)b * 1024 * 2048 + 1024 + h * 64 + (size_t)srow * 2048 + kcolel
      : qkv  + (size_t)b * 1024 * 3072 + 1024 + h * 64 + (size_t)srow * 3072 + kcolel;
  const size_t incA = half ? (size_t)32 * 2048 : (size_t)32 * 3072;
  const uint16_t* srcB = half
      ? vT + ((size_t)hb * 64 + (th >> 6) * 16 + p_) * 1024 + kc * 512 + gg_ * 8
      : sqk1 + (size_t)b * 1024 * 2048 + 1024 + h * 64 + (size_t)srow * 2048 + kcolel;
  const size_t incB = half ? (size_t)32 : (size_t)32 * 2048;
  const int offA = half * 2048 + th * 8;
  const int offB = 4096 + half * 2048 + th * 8;

#define STAGEO(bufi) do { \
    GLDS16(srcA, &Sh[bufi][offA]); \
    GLDS16(srcB, &Sh[bufi][offB]); \
    srcA += incA; srcB += incB; } while (0)

  f32x4 accO[4] = {};
  STAGEO(0);
  int cur = 0;
  for (int kt = 0; kt < 16; kt++) {
    if (kt < 15) { STAGEO(cur ^ 1); WAITVM(2); }
    else WAITVM(0);
    BAR();
    u16x8 pu;
#pragma unroll
    for (int sub = 0; sub < 2; sub++) {
      f32x4 c0 = {}, c1 = {}, c2 = {};
      c0 = mfma32(*(const bf16x8*)&Sh[cur][sub * 1024 + lane * 8],              qf[0][0], c0);
      c0 = mfma32(*(const bf16x8*)&Sh[cur][sub * 1024 + 512 + lane * 8],        qf[0][1], c0);
      c1 = mfma32(*(const bf16x8*)&Sh[cur][2048 + sub * 1024 + lane * 8],       qf[1][0], c1);
      c1 = mfma32(*(const bf16x8*)&Sh[cur][2048 + sub * 1024 + 512 + lane * 8], qf[1][1], c1);
      c2 = mfma32(*(const bf16x8*)&Sh[cur][4096 + sub * 1024 + lane * 8],       qf[2][0], c2);
      c2 = mfma32(*(const bf16x8*)&Sh[cur][4096 + sub * 1024 + 512 + lane * 8], qf[2][1], c2);
#pragma unroll
      for (int r = 0; r < 4; r++) {
        float m = fmaxf(fmaxf(c0[r] * scl2 - lz0, c1[r] * scl2 - lz1),
                        c2[r] * scl2 - lz2);
        pu[sub * 4 + r] = f2b(__builtin_amdgcn_exp2f(m));
      }
    }
    const bf16x8 pf = __builtin_bit_cast(bf16x8, pu);
#pragma unroll
    for (int dt = 0; dt < 4; dt++) {
      bf16x8 vf = *(const bf16x8*)&Sh[cur][6144 + dt * 512 + lane * 8];
      accO[dt] = mfma32(vf, pf, accO[dt]);
    }
    WAITLGKM0;
    BAR();
    cur ^= 1;
  }
#undef STAGEO

  uint16_t* ob = op + (size_t)kc * 2097152 + rq * 1024 + h * 64;
#pragma unroll
  for (int dt = 0; dt < 4; dt++) {
    u16x4 o4;
#pragma unroll
    for (int r = 0; r < 4; r++) o4[r] = f2b(accO[dt][r]);
    *(u16x4*)(ob + dt * 16 + g * 4) = o4;
  }
}

// ---------------- O partial reduce: Ob = bf16(op0 + op1) ----------------
__global__ __launch_bounds__(256) void ored_k(const uint16_t* __restrict__ op0,
                                              const uint16_t* __restrict__ op1,
                                              uint16_t* __restrict__ Ob) {
  int i = (blockIdx.x * 256 + threadIdx.x) * 4;
  u16x4 a = *(const u16x4*)(op0 + i);
  u16x4 b = *(const u16x4*)(op1 + i);
  u16x4 o;
#pragma unroll
  for (int j = 0; j < 4; j++) o[j] = f2b(b2f(a[j]) + b2f(b[j]));
  *(u16x4*)(Ob + i) = o;
}

// ---------------- LayerNorm over rows of 1024 fp32, optional bf16 copy ----------------
template<int WB>
__global__ __launch_bounds__(256) void ln_k(const float* __restrict__ X,
                                            const float* __restrict__ G,
                                            const float* __restrict__ Bt,
                                            float* __restrict__ Yf,
                                            uint16_t* __restrict__ Yb) {
  const int row = blockIdx.x, t = threadIdx.x;
  const int lane = t & 63, w = t >> 6;
  const size_t base = (size_t)row * 1024 + t * 4;
  f32x4 x = *(const f32x4*)(X + base);
  float s  = x[0] + x[1] + x[2] + x[3];
  float s2 = x[0] * x[0] + x[1] * x[1] + x[2] * x[2] + x[3] * x[3];
#pragma unroll
  for (int o = 1; o < 64; o <<= 1) {
    s  += __shfl_xor(s,  o, 64);
    s2 += __shfl_xor(s2, o, 64);
  }
  __shared__ float red[8];
  if (lane == 0) { red[w] = s; red[4 + w] = s2; }
  __syncthreads();
  s  = red[0] + red[1] + red[2] + red[3];
  s2 = red[4] + red[5] + red[6] + red[7];
  const float mean = s * (1.0f / 1024.0f);
  const float rstd = rsqrtf(s2 * (1.0f / 1024.0f) - mean * mean + 1e-5f);
  f32x4 gv = *(const f32x4*)(G + t * 4);
  f32x4 bv = *(const f32x4*)(Bt + t * 4);
  f32x4 y;
#pragma unroll
  for (int i = 0; i < 4; i++) y[i] = (x[i] - mean) * rstd * gv[i] + bv[i];
  *(f32x4*)(Yf + base) = y;
  if constexpr (WB) {
    u16x4 o;
#pragma unroll
    for (int i = 0; i < 4; i++) o[i] = f2b(y[i]);
    *(u16x4*)(Yb + base) = o;
  }
}

// ---------------- host ----------------
extern "C" void kernel_launch(void* const* d_in, const int* in_sizes, int n_in,
                              void* d_out, int out_size, void* d_ws, size_t ws_size,
                              hipStream_t stream) {
  (void)in_sizes; (void)n_in; (void)out_size;
  const float* id_x = (const float*)d_in[0];
  const float* side = (const float*)d_in[1];
  const float* Wq  = (const float*)d_in[3];
  const float* bq  = (const float*)d_in[4];
  const float* Wk  = (const float*)d_in[5];
  const float* bk  = (const float*)d_in[6];
  const float* Wv  = (const float*)d_in[7];
  const float* bv  = (const float*)d_in[8];
  const float* sWq = (const float*)d_in[9];
  const float* sbq = (const float*)d_in[10];
  const float* sWk = (const float*)d_in[11];
  const float* sbk = (const float*)d_in[12];
  const float* Wo  = (const float*)d_in[13];
  const float* bo  = (const float*)d_in[14];
  const float* W1  = (const float*)d_in[15];
  const float* b1  = (const float*)d_in[16];
  const float* W2  = (const float*)d_in[17];
  const float* b2  = (const float*)d_in[18];
  const float* g1  = (const float*)d_in[19];
  const float* be1 = (const float*)d_in[20];
  const float* g2  = (const float*)d_in[21];
  const float* be2 = (const float*)d_in[22];

  char* ws = (char*)d_ws;
  const size_t oWT   = 0;                       // 10x 1024x1024 bf16 = 20,971,520
  const size_t oBias = 20971520;                // 7168 f32 = 28,672
  const size_t oZP   = 21000192;                // 3*65536 f32 = 786,432
  const size_t oC    = 22179840;                // 4 MB: xb -> op0
  const size_t oD    = 26374144;                // 8 MB: sdb -> op1 | Ob
  const size_t oE    = 34762752;                // 32 MB
  const size_t total = oE + 33554432;           // 68,317,184
  if (ws_size < total) return;

  uint16_t* WT    = (uint16_t*)(ws + oWT);
  float*    biasc = (float*)(ws + oBias);
  float*    zp    = (float*)(ws + oZP);
  uint16_t* xb    = (uint16_t*)(ws + oC);
  uint16_t* op0   = (uint16_t*)(ws + oC);          // aliases xb (dead post-proj)
  uint16_t* sdb   = (uint16_t*)(ws + oD);
  uint16_t* Ob    = (uint16_t*)(ws + oD + 4194304);
  char* E = ws + oE;
  uint16_t* qkv  = (uint16_t*)(E);                  // 12 MB
  uint16_t* sqk0 = (uint16_t*)(E + 12582912);       // 8 MB
  uint16_t* sqk1 = (uint16_t*)(E + 20971520);       // 8 MB
  uint16_t* vTp  = (uint16_t*)(E + 29360128);       // 4 MB
  // post-attention aliases (qkv/sqk/vT dead after attn_o):
  float*    x1   = (float*)(E);                     // 8 MB
  float*    x1n  = (float*)(E + 8388608);           // 8 MB
  uint16_t* x1nb = (uint16_t*)(E + 16777216);       // 4 MB
  uint16_t* hb   = (uint16_t*)(E + 20971520);       // 4 MB
  float*    x2   = (float*)(E + 25165824);          // 8 MB

  wtrans_all<<<dim3(32, 32, 17), dim3(32, 8), 0, stream>>>(
      Wq, Wk, Wv, sWq, sWk, sWq + 1048576, sWk + 1048576, Wo, W1, W2, WT,
      bq, bk, bv, sbq, sbk, biasc, id_x, side, xb, sdb);

  proj_k<<<896, 512, 0, stream>>>(xb, sdb, WT, biasc, qkv, sqk0, sqk1, vTp);

  attn_z<<<512, 512, 0, stream>>>(qkv, sqk0, sqk1, zp);
  attn_o<<<512, 512, 0, stream>>>(qkv, sqk0, sqk1, vTp, zp, op0);
  ored_k<<<2048, 256, 0, stream>>>(op0, op0 + 2097152, Ob);

  gemm64_k<EPI_RES><<<dim3(16, 32), 256, 0, stream>>>(Ob, 1024, WT + 7340032, bo, id_x, x1, 1024);
  ln_k<1><<<2048, 256, 0, stream>>>(x1, g1, be1, x1n, x1nb);
  gemm64_k<EPI_GELU><<<dim3(16, 32), 256, 0, stream>>>(x1nb, 1024, WT + 8388608, b1, nullptr, hb, 1024);
  gemm64_k<EPI_RES><<<dim3(16, 32), 256, 0, stream>>>(hb, 1024, WT + 9437184, b2, x1n, x2, 1024);
  ln_k<0><<<2048, 256, 0, stream>>>(x2, g2, be2, (float*)d_out, nullptr);
}